// Round 6
// baseline (517.247 us; speedup 1.0000x reference)
//
#include <hip/hip_runtime.h>
#include <cstdint>
#include <cstddef>

#define D_MODEL 768
#define NBATCH 8
#define SEQLEN 2048
#define NROWS (NBATCH*SEQLEN)   // 16384

typedef __attribute__((ext_vector_type(4))) float  f32x4;
typedef __attribute__((ext_vector_type(8))) __bf16 bf16x8;
typedef __attribute__((ext_vector_type(4))) __bf16 bf16x4;
typedef __attribute__((ext_vector_type(8))) _Float16 f16x8;

#define MFMA16(a,b,c) __builtin_amdgcn_mfma_f32_16x16x32_bf16(a,b,c,0,0,0)
#define SCALE 0.03608439182435161f   // 1/sqrt(768)

// ---------------- workspace layout (bytes) ----------------
static constexpr size_t SZ_ACT = (size_t)NROWS * D_MODEL * 2;       // 25165824
static constexpr size_t OFF_Q    = 0;
static constexpr size_t OFF_K    = OFF_Q + SZ_ACT;
static constexpr size_t OFF_VT   = OFF_K + SZ_ACT;
static constexpr size_t OFF_X2   = OFF_VT + SZ_ACT;                 // fp32
static constexpr size_t OFF_W    = OFF_X2 + (size_t)NROWS*D_MODEL*4;
static constexpr size_t OFF_POOL = OFF_W + (size_t)5*589824*2;      // 131727360
// POOL: h1 @ +0, v @ +SZ_ACT; then S (fp16): 8-batch (67MB) if ws allows, else 4-batch x2

__device__ __forceinline__ float gelu_exact(float x) {
  return 0.5f * x * (1.0f + erff(x * 0.70710678118654752f));
}

// ---------------- weight fp32 -> bf16 ----------------
__global__ __launch_bounds__(256) void k_cvt5(
    const float* __restrict__ s0, const float* __restrict__ s1,
    const float* __restrict__ s2, const float* __restrict__ s3,
    const float* __restrict__ s4, __bf16* __restrict__ dst)
{
  const int wsel = blockIdx.y;
  const float* s = wsel==0 ? s0 : wsel==1 ? s1 : wsel==2 ? s2 : wsel==3 ? s3 : s4;
  const size_t i = ((size_t)blockIdx.x*256 + threadIdx.x)*4;
  float4 v = *(const float4*)(s + i);
  bf16x4 o;
  o[0] = (__bf16)v.x; o[1] = (__bf16)v.y; o[2] = (__bf16)v.z; o[3] = (__bf16)v.w;
  *(bf16x4*)(dst + (size_t)wsel*589824 + i) = o;
}

// ---------------- LayerNorm (wave per row) ----------------
__global__ __launch_bounds__(256) void k_layernorm(
    const float* __restrict__ x, const float* __restrict__ g,
    const float* __restrict__ be, __bf16* __restrict__ out)
{
  const int row  = blockIdx.x*4 + (threadIdx.x>>6);
  const int lane = threadIdx.x & 63;
  const float4* xr = (const float4*)(x + (size_t)row*D_MODEL);
  float4 v[3];
  float s = 0.f, ss = 0.f;
#pragma unroll
  for (int j=0;j<3;j++){
    v[j] = xr[lane + 64*j];
    s  += v[j].x + v[j].y + v[j].z + v[j].w;
    ss += v[j].x*v[j].x + v[j].y*v[j].y + v[j].z*v[j].z + v[j].w*v[j].w;
  }
#pragma unroll
  for (int d=1; d<64; d<<=1){ s += __shfl_xor(s,d); ss += __shfl_xor(ss,d); }
  const float mu   = s  * (1.f/768.f);
  const float var  = ss * (1.f/768.f) - mu*mu;
  const float rstd = rsqrtf(var + 1e-5f);
  __bf16* orow = out + (size_t)row*D_MODEL;
#pragma unroll
  for (int j=0;j<3;j++){
    const int c0 = (lane + 64*j)*4;
    bf16x4 o;
    o[0] = (__bf16)((v[j].x - mu)*rstd*g[c0+0] + be[c0+0]);
    o[1] = (__bf16)((v[j].y - mu)*rstd*g[c0+1] + be[c0+1]);
    o[2] = (__bf16)((v[j].z - mu)*rstd*g[c0+2] + be[c0+2]);
    o[3] = (__bf16)((v[j].w - mu)*rstd*g[c0+3] + be[c0+3]);
    *(bf16x4*)(orow + c0) = o;
  }
}

// ---------------- V transpose: v[b,t,d] -> vT[b,d,t] ----------------
__global__ __launch_bounds__(256) void k_transpose_v(
    const __bf16* __restrict__ v, __bf16* __restrict__ vT)
{
  __shared__ __bf16 tile[64][72];
  const int b = blockIdx.z;
  const int t0 = blockIdx.x*64, d0 = blockIdx.y*64;
  const int tid = threadIdx.x;
  const int rr = (tid>>3)*2, cc = (tid&7)*8;
  const __bf16* src = v + ((size_t)b*SEQLEN + t0)*D_MODEL + d0;
#pragma unroll
  for (int j=0;j<2;j++){
    bf16x8 val = *(const bf16x8*)(src + (size_t)(rr+j)*D_MODEL + cc);
#pragma unroll
    for (int e=0;e<8;e++) tile[cc+e][rr+j] = val[e];
  }
  __syncthreads();
  __bf16* dst = vT + ((size_t)b*D_MODEL + d0)*SEQLEN + t0;
#pragma unroll
  for (int j=0;j<2;j++){
    bf16x8 o;
#pragma unroll
    for (int e=0;e<8;e++) o[e] = tile[rr+j][cc+e];
    *(bf16x8*)(dst + (size_t)(rr+j)*SEQLEN + cc) = o;
  }
}

// ---------------- row softmax, in-place fp16 -> bf16 ----------------
__global__ __launch_bounds__(256) void k_softmax(_Float16* __restrict__ S)
{
  const int row  = blockIdx.x*4 + (threadIdx.x>>6);
  const int lane = threadIdx.x & 63;
  _Float16* sr = S + (size_t)row*SEQLEN + lane*32;
  f16x8 v[4];
#pragma unroll
  for (int j=0;j<4;j++) v[j] = *(const f16x8*)(sr + j*8);
  float f[32];
  float mx = -1e30f;
#pragma unroll
  for (int j=0;j<4;j++)
#pragma unroll
    for (int e=0;e<8;e++){ f[j*8+e] = (float)v[j][e]; mx = fmaxf(mx, f[j*8+e]); }
#pragma unroll
  for (int d=1; d<64; d<<=1) mx = fmaxf(mx, __shfl_xor(mx, d));
  float sum = 0.f;
#pragma unroll
  for (int i=0;i<32;i++){ f[i] = __expf(f[i]-mx); sum += f[i]; }
#pragma unroll
  for (int d=1; d<64; d<<=1) sum += __shfl_xor(sum, d);
  const float inv = 1.f/sum;
  __bf16* pr = (__bf16*)(S + (size_t)row*SEQLEN) + lane*32;
#pragma unroll
  for (int j=0;j<4;j++){
    bf16x8 o;
#pragma unroll
    for (int e=0;e<8;e++) o[e] = (__bf16)(f[j*8+e]*inv);
    *(bf16x8*)(pr + j*8) = o;
  }
}

// =====================================================================
// 8-phase 256x256 GEMM core (NT: C[256][256] = A[256xK] @ B[256xK]^T)
// 8 waves (2x4), BK=64, dbuf LDS 128KB, burst prefetch of tile t+1,
// XOR-swizzled LDS (inverse-swizzled global source, rule #21),
// per-phase: 12 ds_read_b128 -> s_barrier -> setprio(1) 16xMFMA setprio(0)
// -> s_barrier; vmcnt(0) only at K-tile boundaries (loads had ~4 phases
// of compute to land -> near-free).
// acc[mi][ni][r]: row = wr*128+mi*16+l4*4+r, col = wc*64+ni*16+l16.
// =====================================================================
__device__ __forceinline__ void gemm_core8(
    const __bf16* __restrict__ Asrc, const int ldA,
    const __bf16* __restrict__ Bsrc, const int ldB,
    const int nt, f32x4 (&acc)[8][4])
{
  __shared__ __bf16 As[32768];   // 2 bufs x 256 x 64
  __shared__ __bf16 Bs[32768];
  const int tid = threadIdx.x, w = tid>>6, lane = tid&63;
  const int wr = w>>2, wc = w&3, l16 = lane&15, l4 = lane>>4;
  const int rsw = l16 & 7;

#pragma unroll
  for (int mi=0;mi<8;mi++)
#pragma unroll
    for (int ni=0;ni<4;ni++)
#pragma unroll
      for (int r=0;r<4;r++) acc[mi][ni][r] = 0.f;

#define STG8(SB, T_) \
  _Pragma("unroll") \
  for (int j=0;j<4;j++){ \
    const int id = tid + 512*j; \
    const int row = id>>3; \
    const int sc = (id&7) ^ (row&7); \
    const int kb = (T_)*64 + sc*8; \
    const int base = (SB)*16384 + (w*64 + 512*j)*8; \
    __builtin_amdgcn_global_load_lds((const __attribute__((address_space(1))) void*)(Asrc + (size_t)row*ldA + kb), (__attribute__((address_space(3))) void*)(As + base), 16, 0, 0); \
    __builtin_amdgcn_global_load_lds((const __attribute__((address_space(1))) void*)(Bsrc + (size_t)row*ldB + kb), (__attribute__((address_space(3))) void*)(Bs + base), 16, 0, 0); \
  }

#define PH4(SB) \
  _Pragma("unroll") \
  for (int q=0;q<4;q++){ \
    const int qm = q>>1, qn = q&1; \
    bf16x8 af[4][2]; bf16x8 bq_[2][2]; \
    _Pragma("unroll") \
    for (int mi=0;mi<4;mi++){ \
      const int rb = (SB)*16384 + (wr*128 + (qm*4+mi)*16 + l16)*64; \
      af[mi][0] = *(const bf16x8*)(As + rb + ((l4    ) ^ rsw)*8); \
      af[mi][1] = *(const bf16x8*)(As + rb + ((l4 + 4) ^ rsw)*8); \
    } \
    _Pragma("unroll") \
    for (int ni=0;ni<2;ni++){ \
      const int rb = (SB)*16384 + (wc*64 + (qn*2+ni)*16 + l16)*64; \
      bq_[ni][0] = *(const bf16x8*)(Bs + rb + ((l4    ) ^ rsw)*8); \
      bq_[ni][1] = *(const bf16x8*)(Bs + rb + ((l4 + 4) ^ rsw)*8); \
    } \
    __builtin_amdgcn_s_barrier(); \
    __builtin_amdgcn_s_setprio(1); \
    _Pragma("unroll") \
    for (int kk=0;kk<2;kk++) \
      _Pragma("unroll") \
      for (int mi=0;mi<4;mi++) \
        _Pragma("unroll") \
        for (int ni=0;ni<2;ni++) \
          acc[qm*4+mi][qn*2+ni] = MFMA16(af[mi][kk], bq_[ni][kk], acc[qm*4+mi][qn*2+ni]); \
    __builtin_amdgcn_s_setprio(0); \
    if (q<3) __builtin_amdgcn_s_barrier(); \
  }

  STG8(0, 0)
  asm volatile("s_waitcnt vmcnt(0)" ::: "memory");
  __builtin_amdgcn_s_barrier();

  for (int t=0; t<nt; t+=2){
    STG8(1, t+1)
    PH4(0)
    asm volatile("s_waitcnt vmcnt(0)" ::: "memory");
    __builtin_amdgcn_s_barrier();
    if (t+2 < nt){ STG8(0, t+2) }
    PH4(1)
    asm volatile("s_waitcnt vmcnt(0)" ::: "memory");
    __builtin_amdgcn_s_barrier();
  }
#undef STG8
#undef PH4
}

// ---------------- fused QKV (Q pre-scaled) ----------------
__global__ __launch_bounds__(512,1) void k8_qkv(
    const __bf16* __restrict__ A, const __bf16* __restrict__ W,
    const float* __restrict__ bq, const float* __restrict__ bk, const float* __restrict__ bv,
    __bf16* __restrict__ Cq, __bf16* __restrict__ Ck, __bf16* __restrict__ Cv)
{
  const int bm = blockIdx.x/9, bn = blockIdx.x%9;
  f32x4 acc[8][4];
  gemm_core8(A + (size_t)bm*256*D_MODEL, D_MODEL, W + (size_t)bn*256*D_MODEL, D_MODEL, 12, acc);
  const int tid = threadIdx.x, w=tid>>6, lane=tid&63;
  const int wr=w>>2, wc=w&3, l16=lane&15, l4=lane>>4;
  const int seg = (bn*256)/D_MODEL;
  const int colb = bn*256 - seg*D_MODEL + wc*64;
  const float* bias = seg==0?bq:(seg==1?bk:bv);
  __bf16* C = seg==0?Cq:(seg==1?Ck:Cv);
  const int row0 = bm*256 + wr*128;
#pragma unroll
  for (int ni=0;ni<4;ni++){
    const int col = colb + ni*16 + l16;
    const float bb = bias[col];
#pragma unroll
    for (int mi=0;mi<8;mi++)
#pragma unroll
      for (int r=0;r<4;r++){
        const int row = row0 + mi*16 + l4*4 + r;
        float v = acc[mi][ni][r] + bb;
        if (seg==0) v *= SCALE;
        C[(size_t)row*D_MODEL + col] = (__bf16)v;
      }
  }
}

// ---------------- S = Qs @ K^T (fp16 out) ----------------
__global__ __launch_bounds__(512,1) void k8_s(
    const __bf16* __restrict__ Q, const __bf16* __restrict__ K, _Float16* __restrict__ S)
{
  const int bm = blockIdx.x>>3, bn = blockIdx.x&7;
  const size_t bo = (size_t)blockIdx.y * SEQLEN * D_MODEL;
  f32x4 acc[8][4];
  gemm_core8(Q + bo + (size_t)bm*256*D_MODEL, D_MODEL, K + bo + (size_t)bn*256*D_MODEL, D_MODEL, 12, acc);
  const int tid = threadIdx.x, w=tid>>6, lane=tid&63;
  const int wr=w>>2, wc=w&3, l16=lane&15, l4=lane>>4;
  _Float16* Sb = S + (size_t)blockIdx.y*SEQLEN*SEQLEN;
  const int row0 = bm*256 + wr*128, col0 = bn*256 + wc*64;
#pragma unroll
  for (int ni=0;ni<4;ni++){
    const int col = col0 + ni*16 + l16;
#pragma unroll
    for (int mi=0;mi<8;mi++)
#pragma unroll
      for (int r=0;r<4;r++)
        Sb[(size_t)(row0 + mi*16 + l4*4 + r)*SEQLEN + col] = (_Float16)acc[mi][ni][r];
  }
}

// ---------------- O = P @ V + x (fp32 out) ----------------
__global__ __launch_bounds__(512,1) void k8_pv(
    const __bf16* __restrict__ P, const __bf16* __restrict__ VT,
    const float* __restrict__ x, float* __restrict__ x2, int bbase)
{
  const int bm = blockIdx.x/3, bn = blockIdx.x%3;
  const int bidx = bbase + blockIdx.y;
  f32x4 acc[8][4];
  gemm_core8(P + (size_t)blockIdx.y*SEQLEN*SEQLEN + (size_t)bm*256*SEQLEN, SEQLEN,
             VT + (size_t)bidx*D_MODEL*SEQLEN + (size_t)bn*256*SEQLEN, SEQLEN, 32, acc);
  const int tid = threadIdx.x, w=tid>>6, lane=tid&63;
  const int wr=w>>2, wc=w&3, l16=lane&15, l4=lane>>4;
  const size_t row0 = (size_t)bidx*SEQLEN + bm*256 + wr*128;
  const int col0 = bn*256 + wc*64;
#pragma unroll
  for (int ni=0;ni<4;ni++){
    const int col = col0 + ni*16 + l16;
#pragma unroll
    for (int mi=0;mi<8;mi++)
#pragma unroll
      for (int r=0;r<4;r++){
        const size_t row = row0 + mi*16 + l4*4 + r;
        x2[row*D_MODEL + col] = acc[mi][ni][r] + x[row*D_MODEL + col];
      }
  }
}

// ---------------- MLP GEMM: RES=0 bf16+GELU, RES=1 f32+GELU+resid ----------------
template<int RES>
__global__ __launch_bounds__(512,1) void k8_mlp(
    const __bf16* __restrict__ A, const __bf16* __restrict__ W,
    const float* __restrict__ bias, const float* __restrict__ resid, void* __restrict__ out)
{
  const int bm = blockIdx.x/3, bn = blockIdx.x%3;
  f32x4 acc[8][4];
  gemm_core8(A + (size_t)bm*256*D_MODEL, D_MODEL, W + (size_t)bn*256*D_MODEL, D_MODEL, 12, acc);
  const int tid = threadIdx.x, w=tid>>6, lane=tid&63;
  const int wr=w>>2, wc=w&3, l16=lane&15, l4=lane>>4;
  const int row0 = bm*256 + wr*128, col0 = bn*256 + wc*64;
#pragma unroll
  for (int ni=0;ni<4;ni++){
    const int col = col0 + ni*16 + l16;
    const float bb = bias[col];
#pragma unroll
    for (int mi=0;mi<8;mi++)
#pragma unroll
      for (int r=0;r<4;r++){
        const int row = row0 + mi*16 + l4*4 + r;
        float v = gelu_exact(acc[mi][ni][r] + bb);
        if (RES) ((float*)out)[(size_t)row*D_MODEL + col] = v + resid[(size_t)row*D_MODEL + col];
        else     ((__bf16*)out)[(size_t)row*D_MODEL + col] = (__bf16)v;
      }
  }
}

// ---------------- launch ----------------
extern "C" void kernel_launch(void* const* d_in, const int* in_sizes, int n_in,
                              void* d_out, int out_size, void* d_ws, size_t ws_size,
                              hipStream_t stream)
{
  const float* x   = (const float*)d_in[0];
  const float* Wq  = (const float*)d_in[1];
  const float* bq  = (const float*)d_in[2];
  const float* Wk  = (const float*)d_in[3];
  const float* bk  = (const float*)d_in[4];
  const float* Wv  = (const float*)d_in[5];
  const float* bv  = (const float*)d_in[6];
  const float* W1  = (const float*)d_in[7];
  const float* b1  = (const float*)d_in[8];
  const float* W2  = (const float*)d_in[9];
  const float* b2  = (const float*)d_in[10];
  const float* g1  = (const float*)d_in[11];
  const float* be1 = (const float*)d_in[12];
  const float* g2  = (const float*)d_in[13];
  const float* be2 = (const float*)d_in[14];
  (void)in_sizes; (void)n_in; (void)out_size;

  char* ws = (char*)d_ws;
  __bf16*   qb  = (__bf16*)(ws + OFF_Q);
  __bf16*   kb  = (__bf16*)(ws + OFF_K);
  __bf16*   vT  = (__bf16*)(ws + OFF_VT);
  float*    x2  = (float*)(ws + OFF_X2);
  __bf16*   wbf = (__bf16*)(ws + OFF_W);
  __bf16*   h1  = (__bf16*)(ws + OFF_POOL);
  __bf16*   vb  = (__bf16*)(ws + OFF_POOL + SZ_ACT);
  _Float16* Sp  = (_Float16*)(ws + OFF_POOL);
  __bf16*   h2  = h1;
  __bf16*   h3  = qb;

  const bool big = ws_size >= OFF_POOL + (size_t)NBATCH*SEQLEN*SEQLEN*2;

  k_cvt5<<<dim3(576,5,1),256,0,stream>>>(Wq,Wk,Wv,W1,W2,wbf);
  k_layernorm<<<dim3(4096),256,0,stream>>>(x, g1, be1, h1);
  k8_qkv<<<dim3(576),512,0,stream>>>(h1, wbf, bq, bk, bv, qb, kb, vb);
  k_transpose_v<<<dim3(32,12,8),256,0,stream>>>(vb, vT);

  if (big){
    k8_s<<<dim3(64,8),512,0,stream>>>(qb, kb, Sp);
    k_softmax<<<dim3(4096),256,0,stream>>>(Sp);
    k8_pv<<<dim3(24,8),512,0,stream>>>((const __bf16*)Sp, vT, x, x2, 0);
  } else {
    for (int c=0;c<2;c++){
      const size_t qoff = (size_t)c*4*SEQLEN*D_MODEL;
      k8_s<<<dim3(64,4),512,0,stream>>>(qb + qoff, kb + qoff, Sp);
      k_softmax<<<dim3(2048),256,0,stream>>>(Sp);
      k8_pv<<<dim3(24,4),512,0,stream>>>((const __bf16*)Sp, vT, x, x2, c*4);
    }
  }

  k_layernorm<<<dim3(4096),256,0,stream>>>(x2, g2, be2, h2);
  k8_mlp<0><<<dim3(192),512,0,stream>>>(h2, wbf + (size_t)3*589824, b1, nullptr, h3);
  k8_mlp<1><<<dim3(192),512,0,stream>>>(h3, wbf + (size_t)4*589824, b2, x2, d_out);
}

// Round 7
// 501.536 us; speedup vs baseline: 1.0313x; 1.0313x over previous
//
#include <hip/hip_runtime.h>
#include <cstdint>
#include <cstddef>

#define D_MODEL 768
#define NBATCH 8
#define SEQLEN 2048
#define NROWS (NBATCH*SEQLEN)   // 16384

typedef __attribute__((ext_vector_type(4))) float  f32x4;
typedef __attribute__((ext_vector_type(8))) __bf16 bf16x8;
typedef __attribute__((ext_vector_type(4))) __bf16 bf16x4;
typedef __attribute__((ext_vector_type(8))) _Float16 f16x8;

#define MFMA16(a,b,c) __builtin_amdgcn_mfma_f32_16x16x32_bf16(a,b,c,0,0,0)
#define SCALE 0.03608439182435161f   // 1/sqrt(768)

// ---------------- workspace layout (bytes) ----------------
static constexpr size_t SZ_ACT = (size_t)NROWS * D_MODEL * 2;       // 25165824
static constexpr size_t OFF_Q    = 0;
static constexpr size_t OFF_K    = OFF_Q + SZ_ACT;
static constexpr size_t OFF_VT   = OFF_K + SZ_ACT;
static constexpr size_t OFF_X2   = OFF_VT + SZ_ACT;                 // fp32
static constexpr size_t OFF_W    = OFF_X2 + (size_t)NROWS*D_MODEL*4;
static constexpr size_t OFF_POOL = OFF_W + (size_t)5*589824*2;      // 131727360

__device__ __forceinline__ float gelu_exact(float x) {
  return 0.5f * x * (1.0f + erff(x * 0.70710678118654752f));
}

// ---------------- weight fp32 -> bf16 ----------------
__global__ __launch_bounds__(256) void k_cvt5(
    const float* __restrict__ s0, const float* __restrict__ s1,
    const float* __restrict__ s2, const float* __restrict__ s3,
    const float* __restrict__ s4, __bf16* __restrict__ dst)
{
  const int wsel = blockIdx.y;
  const float* s = wsel==0 ? s0 : wsel==1 ? s1 : wsel==2 ? s2 : wsel==3 ? s3 : s4;
  const size_t i = ((size_t)blockIdx.x*256 + threadIdx.x)*4;
  float4 v = *(const float4*)(s + i);
  bf16x4 o;
  o[0] = (__bf16)v.x; o[1] = (__bf16)v.y; o[2] = (__bf16)v.z; o[3] = (__bf16)v.w;
  *(bf16x4*)(dst + (size_t)wsel*589824 + i) = o;
}

// ---------------- LayerNorm (wave per row) ----------------
__global__ __launch_bounds__(256) void k_layernorm(
    const float* __restrict__ x, const float* __restrict__ g,
    const float* __restrict__ be, __bf16* __restrict__ out)
{
  const int row  = blockIdx.x*4 + (threadIdx.x>>6);
  const int lane = threadIdx.x & 63;
  const float4* xr = (const float4*)(x + (size_t)row*D_MODEL);
  float4 v[3];
  float s = 0.f, ss = 0.f;
#pragma unroll
  for (int j=0;j<3;j++){
    v[j] = xr[lane + 64*j];
    s  += v[j].x + v[j].y + v[j].z + v[j].w;
    ss += v[j].x*v[j].x + v[j].y*v[j].y + v[j].z*v[j].z + v[j].w*v[j].w;
  }
#pragma unroll
  for (int d=1; d<64; d<<=1){ s += __shfl_xor(s,d); ss += __shfl_xor(ss,d); }
  const float mu   = s  * (1.f/768.f);
  const float var  = ss * (1.f/768.f) - mu*mu;
  const float rstd = rsqrtf(var + 1e-5f);
  __bf16* orow = out + (size_t)row*D_MODEL;
#pragma unroll
  for (int j=0;j<3;j++){
    const int c0 = (lane + 64*j)*4;
    bf16x4 o;
    o[0] = (__bf16)((v[j].x - mu)*rstd*g[c0+0] + be[c0+0]);
    o[1] = (__bf16)((v[j].y - mu)*rstd*g[c0+1] + be[c0+1]);
    o[2] = (__bf16)((v[j].z - mu)*rstd*g[c0+2] + be[c0+2]);
    o[3] = (__bf16)((v[j].w - mu)*rstd*g[c0+3] + be[c0+3]);
    *(bf16x4*)(orow + c0) = o;
  }
}

// ---------------- V transpose: v[b,t,d] -> vT[b,d,t] ----------------
__global__ __launch_bounds__(256) void k_transpose_v(
    const __bf16* __restrict__ v, __bf16* __restrict__ vT)
{
  __shared__ __bf16 tile[64][72];
  const int b = blockIdx.z;
  const int t0 = blockIdx.x*64, d0 = blockIdx.y*64;
  const int tid = threadIdx.x;
  const int rr = (tid>>3)*2, cc = (tid&7)*8;
  const __bf16* src = v + ((size_t)b*SEQLEN + t0)*D_MODEL + d0;
#pragma unroll
  for (int j=0;j<2;j++){
    bf16x8 val = *(const bf16x8*)(src + (size_t)(rr+j)*D_MODEL + cc);
#pragma unroll
    for (int e=0;e<8;e++) tile[cc+e][rr+j] = val[e];
  }
  __syncthreads();
  __bf16* dst = vT + ((size_t)b*D_MODEL + d0)*SEQLEN + t0;
#pragma unroll
  for (int j=0;j<2;j++){
    bf16x8 o;
#pragma unroll
    for (int e=0;e<8;e++) o[e] = tile[rr+j][cc+e];
    *(bf16x8*)(dst + (size_t)(rr+j)*SEQLEN + cc) = o;
  }
}

// ---------------- row softmax, in-place fp16 -> bf16 ----------------
__global__ __launch_bounds__(256) void k_softmax(_Float16* __restrict__ S)
{
  const int row  = blockIdx.x*4 + (threadIdx.x>>6);
  const int lane = threadIdx.x & 63;
  _Float16* sr = S + (size_t)row*SEQLEN + lane*32;
  f16x8 v[4];
#pragma unroll
  for (int j=0;j<4;j++) v[j] = *(const f16x8*)(sr + j*8);
  float f[32];
  float mx = -1e30f;
#pragma unroll
  for (int j=0;j<4;j++)
#pragma unroll
    for (int e=0;e<8;e++){ f[j*8+e] = (float)v[j][e]; mx = fmaxf(mx, f[j*8+e]); }
#pragma unroll
  for (int d=1; d<64; d<<=1) mx = fmaxf(mx, __shfl_xor(mx, d));
  float sum = 0.f;
#pragma unroll
  for (int i=0;i<32;i++){ f[i] = __expf(f[i]-mx); sum += f[i]; }
#pragma unroll
  for (int d=1; d<64; d<<=1) sum += __shfl_xor(sum, d);
  const float inv = 1.f/sum;
  __bf16* pr = (__bf16*)(S + (size_t)row*SEQLEN) + lane*32;
#pragma unroll
  for (int j=0;j<4;j++){
    bf16x8 o;
#pragma unroll
    for (int e=0;e<8;e++) o[e] = (__bf16)(f[j*8+e]*inv);
    *(bf16x8*)(pr + j*8) = o;
  }
}

// =====================================================================
// Quad-buffered BK=32 256x256 NT GEMM core with COUNTED vmcnt (T3+T4).
// 8 waves (2x4). LDS = 4 bufs x (A 16KB + B 16KB) = 128 KB.
// Per tile/wave: 4 global_load_lds (prefetch t+3), 12 ds_read_b128,
// 32 MFMA, ONE barrier. Steady-state wait = vmcnt(8): tiles t+1,t+2
// stay in flight across barriers (never drain). Prefetch lead ~3 tiles
// covers HBM latency. XOR swizzle c ^= (row&3)^((row>>2)&1) applied on
// BOTH global-source and LDS-read (rule #21) -> ~2-way max (free).
// Safety: a wave reaches barrier t only after its tile-(t-1) ds_reads
// drained (lgkmcnt precedes its MFMAs), and STG(t+3) (overwriting
// buf[(t-1)&3]) issues only after that barrier.
// acc[mi][ni][r]: row = wr*128+mi*16+l4*4+r, col = wc*64+ni*16+l16.
// =====================================================================
__device__ __forceinline__ void gemm_core_q4(
    const __bf16* __restrict__ Asrc, const int ldA,
    const __bf16* __restrict__ Bsrc, const int ldB,
    const int nt, f32x4 (&acc)[8][4])
{
  __shared__ __bf16 As[4*8192];   // 4 bufs x 256 rows x 32 cols
  __shared__ __bf16 Bs[4*8192];
  const int tid = threadIdx.x, w = tid>>6, lane = tid&63;
  const int wr = w>>2, wc = w&3, l16 = lane&15, l4 = lane>>4;
  const int rsw = (l16&3) ^ ((l16>>2)&1);   // swizzle(row) depends on row&7 = l16&7
  const int rdc = (l4 ^ rsw)*8;             // swizzled read chunk offset (elems)

#pragma unroll
  for (int mi=0;mi<8;mi++)
#pragma unroll
    for (int ni=0;ni<4;ni++)
#pragma unroll
      for (int r=0;r<4;r++) acc[mi][ni][r] = 0.f;

  // stage tile T_ into buffer SB: per wave 2 A-instrs + 2 B-instrs.
  // LDS dest is wave-uniform base (HW adds lane*16); global src is per-lane
  // inverse-swizzled.
#define STG(SB, T_) { \
  _Pragma("unroll") \
  for (int j_=0;j_<2;j_++){ \
    const int cid = (w + 8*j_)*64 + lane; \
    const int row_ = cid>>2, cc_ = cid&3; \
    const int sc_ = cc_ ^ (row_&3) ^ ((row_>>2)&1); \
    const int ub  = (SB)*8192 + (w + 8*j_)*512; \
    __builtin_amdgcn_global_load_lds( \
      (const __attribute__((address_space(1))) void*)(Asrc + (size_t)row_*ldA + (T_)*32 + sc_*8), \
      (__attribute__((address_space(3))) void*)(As + ub), 16, 0, 0); \
    __builtin_amdgcn_global_load_lds( \
      (const __attribute__((address_space(1))) void*)(Bsrc + (size_t)row_*ldB + (T_)*32 + sc_*8), \
      (__attribute__((address_space(3))) void*)(Bs + ub), 16, 0, 0); \
  } }

  STG(0, 0) STG(1, 1) STG(2, 2)   // 12 vmem instrs in flight

  for (int t=0; t<nt; ++t){
    if (t+2 < nt)      asm volatile("s_waitcnt vmcnt(8)" ::: "memory");
    else if (t+1 < nt) asm volatile("s_waitcnt vmcnt(4)" ::: "memory");
    else               asm volatile("s_waitcnt vmcnt(0)" ::: "memory");
    __builtin_amdgcn_s_barrier();
    if (t+3 < nt) STG((t+3)&3, t+3)
    const int sb = t&3;
    bf16x8 af[8], bq[4];
#pragma unroll
    for (int mi=0;mi<8;mi++)
      af[mi] = *(const bf16x8*)(As + sb*8192 + (wr*128 + mi*16 + l16)*32 + rdc);
#pragma unroll
    for (int ni=0;ni<4;ni++)
      bq[ni] = *(const bf16x8*)(Bs + sb*8192 + (wc*64 + ni*16 + l16)*32 + rdc);
    __builtin_amdgcn_s_setprio(1);
#pragma unroll
    for (int mi=0;mi<8;mi++)
#pragma unroll
      for (int ni=0;ni<4;ni++)
        acc[mi][ni] = MFMA16(af[mi], bq[ni], acc[mi][ni]);
    __builtin_amdgcn_s_setprio(0);
  }
#undef STG
}

// ---------------- fused QKV (Q pre-scaled) ----------------
__global__ __launch_bounds__(512,1) void k8_qkv(
    const __bf16* __restrict__ A, const __bf16* __restrict__ W,
    const float* __restrict__ bq, const float* __restrict__ bk, const float* __restrict__ bv,
    __bf16* __restrict__ Cq, __bf16* __restrict__ Ck, __bf16* __restrict__ Cv)
{
  const int bm = blockIdx.x/9, bn = blockIdx.x%9;
  f32x4 acc[8][4];
  gemm_core_q4(A + (size_t)bm*256*D_MODEL, D_MODEL, W + (size_t)bn*256*D_MODEL, D_MODEL, 24, acc);
  const int tid = threadIdx.x, w=tid>>6, lane=tid&63;
  const int wr=w>>2, wc=w&3, l16=lane&15, l4=lane>>4;
  const int seg = (bn*256)/D_MODEL;
  const int colb = bn*256 - seg*D_MODEL + wc*64;
  const float* bias = seg==0?bq:(seg==1?bk:bv);
  __bf16* C = seg==0?Cq:(seg==1?Ck:Cv);
  const int row0 = bm*256 + wr*128;
#pragma unroll
  for (int ni=0;ni<4;ni++){
    const int col = colb + ni*16 + l16;
    const float bb = bias[col];
#pragma unroll
    for (int mi=0;mi<8;mi++)
#pragma unroll
      for (int r=0;r<4;r++){
        const int row = row0 + mi*16 + l4*4 + r;
        float v = acc[mi][ni][r] + bb;
        if (seg==0) v *= SCALE;
        C[(size_t)row*D_MODEL + col] = (__bf16)v;
      }
  }
}

// ---------------- S = Qs @ K^T (fp16 out) ----------------
__global__ __launch_bounds__(512,1) void k8_s(
    const __bf16* __restrict__ Q, const __bf16* __restrict__ K, _Float16* __restrict__ S)
{
  const int bm = blockIdx.x>>3, bn = blockIdx.x&7;
  const size_t bo = (size_t)blockIdx.y * SEQLEN * D_MODEL;
  f32x4 acc[8][4];
  gemm_core_q4(Q + bo + (size_t)bm*256*D_MODEL, D_MODEL, K + bo + (size_t)bn*256*D_MODEL, D_MODEL, 24, acc);
  const int tid = threadIdx.x, w=tid>>6, lane=tid&63;
  const int wr=w>>2, wc=w&3, l16=lane&15, l4=lane>>4;
  _Float16* Sb = S + (size_t)blockIdx.y*SEQLEN*SEQLEN;
  const int row0 = bm*256 + wr*128, col0 = bn*256 + wc*64;
#pragma unroll
  for (int ni=0;ni<4;ni++){
    const int col = col0 + ni*16 + l16;
#pragma unroll
    for (int mi=0;mi<8;mi++)
#pragma unroll
      for (int r=0;r<4;r++)
        Sb[(size_t)(row0 + mi*16 + l4*4 + r)*SEQLEN + col] = (_Float16)acc[mi][ni][r];
  }
}

// ---------------- O = P @ V + x (fp32 out) ----------------
__global__ __launch_bounds__(512,1) void k8_pv(
    const __bf16* __restrict__ P, const __bf16* __restrict__ VT,
    const float* __restrict__ x, float* __restrict__ x2, int bbase)
{
  const int bm = blockIdx.x/3, bn = blockIdx.x%3;
  const int bidx = bbase + blockIdx.y;
  f32x4 acc[8][4];
  gemm_core_q4(P + (size_t)blockIdx.y*SEQLEN*SEQLEN + (size_t)bm*256*SEQLEN, SEQLEN,
               VT + (size_t)bidx*D_MODEL*SEQLEN + (size_t)bn*256*SEQLEN, SEQLEN, 64, acc);
  const int tid = threadIdx.x, w=tid>>6, lane=tid&63;
  const int wr=w>>2, wc=w&3, l16=lane&15, l4=lane>>4;
  const size_t row0 = (size_t)bidx*SEQLEN + bm*256 + wr*128;
  const int col0 = bn*256 + wc*64;
#pragma unroll
  for (int ni=0;ni<4;ni++){
    const int col = col0 + ni*16 + l16;
#pragma unroll
    for (int mi=0;mi<8;mi++)
#pragma unroll
      for (int r=0;r<4;r++){
        const size_t row = row0 + mi*16 + l4*4 + r;
        x2[row*D_MODEL + col] = acc[mi][ni][r] + x[row*D_MODEL + col];
      }
  }
}

// ---------------- MLP GEMM: RES=0 bf16+GELU, RES=1 f32+GELU+resid ----------------
template<int RES>
__global__ __launch_bounds__(512,1) void k8_mlp(
    const __bf16* __restrict__ A, const __bf16* __restrict__ W,
    const float* __restrict__ bias, const float* __restrict__ resid, void* __restrict__ out)
{
  const int bm = blockIdx.x/3, bn = blockIdx.x%3;
  f32x4 acc[8][4];
  gemm_core_q4(A + (size_t)bm*256*D_MODEL, D_MODEL, W + (size_t)bn*256*D_MODEL, D_MODEL, 24, acc);
  const int tid = threadIdx.x, w=tid>>6, lane=tid&63;
  const int wr=w>>2, wc=w&3, l16=lane&15, l4=lane>>4;
  const int row0 = bm*256 + wr*128, col0 = bn*256 + wc*64;
#pragma unroll
  for (int ni=0;ni<4;ni++){
    const int col = col0 + ni*16 + l16;
    const float bb = bias[col];
#pragma unroll
    for (int mi=0;mi<8;mi++)
#pragma unroll
      for (int r=0;r<4;r++){
        const int row = row0 + mi*16 + l4*4 + r;
        float v = gelu_exact(acc[mi][ni][r] + bb);
        if (RES) ((float*)out)[(size_t)row*D_MODEL + col] = v + resid[(size_t)row*D_MODEL + col];
        else     ((__bf16*)out)[(size_t)row*D_MODEL + col] = (__bf16)v;
      }
  }
}

// ---------------- launch ----------------
extern "C" void kernel_launch(void* const* d_in, const int* in_sizes, int n_in,
                              void* d_out, int out_size, void* d_ws, size_t ws_size,
                              hipStream_t stream)
{
  const float* x   = (const float*)d_in[0];
  const float* Wq  = (const float*)d_in[1];
  const float* bq  = (const float*)d_in[2];
  const float* Wk  = (const float*)d_in[3];
  const float* bk  = (const float*)d_in[4];
  const float* Wv  = (const float*)d_in[5];
  const float* bv  = (const float*)d_in[6];
  const float* W1  = (const float*)d_in[7];
  const float* b1  = (const float*)d_in[8];
  const float* W2  = (const float*)d_in[9];
  const float* b2  = (const float*)d_in[10];
  const float* g1  = (const float*)d_in[11];
  const float* be1 = (const float*)d_in[12];
  const float* g2  = (const float*)d_in[13];
  const float* be2 = (const float*)d_in[14];
  (void)in_sizes; (void)n_in; (void)out_size;

  char* ws = (char*)d_ws;
  __bf16*   qb  = (__bf16*)(ws + OFF_Q);
  __bf16*   kb  = (__bf16*)(ws + OFF_K);
  __bf16*   vT  = (__bf16*)(ws + OFF_VT);
  float*    x2  = (float*)(ws + OFF_X2);
  __bf16*   wbf = (__bf16*)(ws + OFF_W);
  __bf16*   h1  = (__bf16*)(ws + OFF_POOL);
  __bf16*   vb  = (__bf16*)(ws + OFF_POOL + SZ_ACT);
  _Float16* Sp  = (_Float16*)(ws + OFF_POOL);
  __bf16*   h2  = h1;
  __bf16*   h3  = qb;

  const bool big = ws_size >= OFF_POOL + (size_t)NBATCH*SEQLEN*SEQLEN*2;

  k_cvt5<<<dim3(576,5,1),256,0,stream>>>(Wq,Wk,Wv,W1,W2,wbf);
  k_layernorm<<<dim3(4096),256,0,stream>>>(x, g1, be1, h1);
  k8_qkv<<<dim3(576),512,0,stream>>>(h1, wbf, bq, bk, bv, qb, kb, vb);
  k_transpose_v<<<dim3(32,12,8),256,0,stream>>>(vb, vT);

  if (big){
    k8_s<<<dim3(64,8),512,0,stream>>>(qb, kb, Sp);
    k_softmax<<<dim3(4096),256,0,stream>>>(Sp);
    k8_pv<<<dim3(24,8),512,0,stream>>>((const __bf16*)Sp, vT, x, x2, 0);
  } else {
    for (int c=0;c<2;c++){
      const size_t qoff = (size_t)c*4*SEQLEN*D_MODEL;
      k8_s<<<dim3(64,4),512,0,stream>>>(qb + qoff, kb + qoff, Sp);
      k_softmax<<<dim3(2048),256,0,stream>>>(Sp);
      k8_pv<<<dim3(24,4),512,0,stream>>>((const __bf16*)Sp, vT, x, x2, c*4);
    }
  }

  k_layernorm<<<dim3(4096),256,0,stream>>>(x2, g2, be2, h2);
  k8_mlp<0><<<dim3(192),512,0,stream>>>(h2, wbf + (size_t)3*589824, b1, nullptr, h3);
  k8_mlp<1><<<dim3(192),512,0,stream>>>(h3, wbf + (size_t)4*589824, b2, x2, d_out);
}

// Round 8
// 480.451 us; speedup vs baseline: 1.0766x; 1.0439x over previous
//
#include <hip/hip_runtime.h>
#include <cstdint>
#include <cstddef>

#define D_MODEL 768
#define NBATCH 8
#define SEQLEN 2048
#define NROWS (NBATCH*SEQLEN)   // 16384

typedef __attribute__((ext_vector_type(4))) float  f32x4;
typedef __attribute__((ext_vector_type(8))) __bf16 bf16x8;
typedef __attribute__((ext_vector_type(4))) __bf16 bf16x4;
typedef __attribute__((ext_vector_type(8))) _Float16 f16x8;

#define MFMA16(a,b,c) __builtin_amdgcn_mfma_f32_16x16x32_bf16(a,b,c,0,0,0)
#define SCALE 0.03608439182435161f   // 1/sqrt(768)

// ---------------- workspace layout (bytes) ----------------
static constexpr size_t SZ_ACT = (size_t)NROWS * D_MODEL * 2;       // 25165824
static constexpr size_t OFF_Q    = 0;
static constexpr size_t OFF_K    = OFF_Q + SZ_ACT;
static constexpr size_t OFF_VT   = OFF_K + SZ_ACT;
static constexpr size_t OFF_X2   = OFF_VT + SZ_ACT;                 // fp32
static constexpr size_t OFF_W    = OFF_X2 + (size_t)NROWS*D_MODEL*4;
static constexpr size_t OFF_POOL = OFF_W + (size_t)5*589824*2;      // 131727360

__device__ __forceinline__ float gelu_exact(float x) {
  return 0.5f * x * (1.0f + erff(x * 0.70710678118654752f));
}

// bijective XCD chunk remap: physical p -> logical L so that logical blocks
// [x*(N/8), (x+1)*(N/8)) all run on XCD x (HW round-robins p%8 across XCDs).
__device__ __forceinline__ int xcd_remap(int p, int chunk) {
  return (p & 7) * chunk + (p >> 3);
}

// ---------------- weight fp32 -> bf16 ----------------
__global__ __launch_bounds__(256) void k_cvt5(
    const float* __restrict__ s0, const float* __restrict__ s1,
    const float* __restrict__ s2, const float* __restrict__ s3,
    const float* __restrict__ s4, __bf16* __restrict__ dst)
{
  const int wsel = blockIdx.y;
  const float* s = wsel==0 ? s0 : wsel==1 ? s1 : wsel==2 ? s2 : wsel==3 ? s3 : s4;
  const size_t i = ((size_t)blockIdx.x*256 + threadIdx.x)*4;
  float4 v = *(const float4*)(s + i);
  bf16x4 o;
  o[0] = (__bf16)v.x; o[1] = (__bf16)v.y; o[2] = (__bf16)v.z; o[3] = (__bf16)v.w;
  *(bf16x4*)(dst + (size_t)wsel*589824 + i) = o;
}

// ---------------- LayerNorm (wave per row) ----------------
__global__ __launch_bounds__(256) void k_layernorm(
    const float* __restrict__ x, const float* __restrict__ g,
    const float* __restrict__ be, __bf16* __restrict__ out)
{
  const int row  = blockIdx.x*4 + (threadIdx.x>>6);
  const int lane = threadIdx.x & 63;
  const float4* xr = (const float4*)(x + (size_t)row*D_MODEL);
  float4 v[3];
  float s = 0.f, ss = 0.f;
#pragma unroll
  for (int j=0;j<3;j++){
    v[j] = xr[lane + 64*j];
    s  += v[j].x + v[j].y + v[j].z + v[j].w;
    ss += v[j].x*v[j].x + v[j].y*v[j].y + v[j].z*v[j].z + v[j].w*v[j].w;
  }
#pragma unroll
  for (int d=1; d<64; d<<=1){ s += __shfl_xor(s,d); ss += __shfl_xor(ss,d); }
  const float mu   = s  * (1.f/768.f);
  const float var  = ss * (1.f/768.f) - mu*mu;
  const float rstd = rsqrtf(var + 1e-5f);
  __bf16* orow = out + (size_t)row*D_MODEL;
#pragma unroll
  for (int j=0;j<3;j++){
    const int c0 = (lane + 64*j)*4;
    bf16x4 o;
    o[0] = (__bf16)((v[j].x - mu)*rstd*g[c0+0] + be[c0+0]);
    o[1] = (__bf16)((v[j].y - mu)*rstd*g[c0+1] + be[c0+1]);
    o[2] = (__bf16)((v[j].z - mu)*rstd*g[c0+2] + be[c0+2]);
    o[3] = (__bf16)((v[j].w - mu)*rstd*g[c0+3] + be[c0+3]);
    *(bf16x4*)(orow + c0) = o;
  }
}

// ---------------- V transpose: v[b,t,d] -> vT[b,d,t] ----------------
__global__ __launch_bounds__(256) void k_transpose_v(
    const __bf16* __restrict__ v, __bf16* __restrict__ vT)
{
  __shared__ __bf16 tile[64][72];
  const int b = blockIdx.z;
  const int t0 = blockIdx.x*64, d0 = blockIdx.y*64;
  const int tid = threadIdx.x;
  const int rr = (tid>>3)*2, cc = (tid&7)*8;
  const __bf16* src = v + ((size_t)b*SEQLEN + t0)*D_MODEL + d0;
#pragma unroll
  for (int j=0;j<2;j++){
    bf16x8 val = *(const bf16x8*)(src + (size_t)(rr+j)*D_MODEL + cc);
#pragma unroll
    for (int e=0;e<8;e++) tile[cc+e][rr+j] = val[e];
  }
  __syncthreads();
  __bf16* dst = vT + ((size_t)b*D_MODEL + d0)*SEQLEN + t0;
#pragma unroll
  for (int j=0;j<2;j++){
    bf16x8 o;
#pragma unroll
    for (int e=0;e<8;e++) o[e] = tile[rr+j][cc+e];
    *(bf16x8*)(dst + (size_t)(rr+j)*SEQLEN + cc) = o;
  }
}

// ---------------- row softmax, in-place fp16 -> bf16 ----------------
__global__ __launch_bounds__(256) void k_softmax(_Float16* __restrict__ S)
{
  const int row  = blockIdx.x*4 + (threadIdx.x>>6);
  const int lane = threadIdx.x & 63;
  _Float16* sr = S + (size_t)row*SEQLEN + lane*32;
  f16x8 v[4];
#pragma unroll
  for (int j=0;j<4;j++) v[j] = *(const f16x8*)(sr + j*8);
  float f[32];
  float mx = -1e30f;
#pragma unroll
  for (int j=0;j<4;j++)
#pragma unroll
    for (int e=0;e<8;e++){ f[j*8+e] = (float)v[j][e]; mx = fmaxf(mx, f[j*8+e]); }
#pragma unroll
  for (int d=1; d<64; d<<=1) mx = fmaxf(mx, __shfl_xor(mx, d));
  float sum = 0.f;
#pragma unroll
  for (int i=0;i<32;i++){ f[i] = __expf(f[i]-mx); sum += f[i]; }
#pragma unroll
  for (int d=1; d<64; d<<=1) sum += __shfl_xor(sum, d);
  const float inv = 1.f/sum;
  __bf16* pr = (__bf16*)(S + (size_t)row*SEQLEN) + lane*32;
#pragma unroll
  for (int j=0;j<4;j++){
    bf16x8 o;
#pragma unroll
    for (int e=0;e<8;e++) o[e] = (__bf16)(f[j*8+e]*inv);
    *(bf16x8*)(pr + j*8) = o;
  }
}

// =====================================================================
// Quad-buffered BK=32 256x256 NT GEMM core with COUNTED vmcnt (T3+T4).
// (unchanged from round 7 — see comments there; this round isolates T1)
// =====================================================================
__device__ __forceinline__ void gemm_core_q4(
    const __bf16* __restrict__ Asrc, const int ldA,
    const __bf16* __restrict__ Bsrc, const int ldB,
    const int nt, f32x4 (&acc)[8][4])
{
  __shared__ __bf16 As[4*8192];   // 4 bufs x 256 rows x 32 cols
  __shared__ __bf16 Bs[4*8192];
  const int tid = threadIdx.x, w = tid>>6, lane = tid&63;
  const int wr = w>>2, wc = w&3, l16 = lane&15, l4 = lane>>4;
  const int rsw = (l16&3) ^ ((l16>>2)&1);
  const int rdc = (l4 ^ rsw)*8;

#pragma unroll
  for (int mi=0;mi<8;mi++)
#pragma unroll
    for (int ni=0;ni<4;ni++)
#pragma unroll
      for (int r=0;r<4;r++) acc[mi][ni][r] = 0.f;

#define STG(SB, T_) { \
  _Pragma("unroll") \
  for (int j_=0;j_<2;j_++){ \
    const int cid = (w + 8*j_)*64 + lane; \
    const int row_ = cid>>2, cc_ = cid&3; \
    const int sc_ = cc_ ^ (row_&3) ^ ((row_>>2)&1); \
    const int ub  = (SB)*8192 + (w + 8*j_)*512; \
    __builtin_amdgcn_global_load_lds( \
      (const __attribute__((address_space(1))) void*)(Asrc + (size_t)row_*ldA + (T_)*32 + sc_*8), \
      (__attribute__((address_space(3))) void*)(As + ub), 16, 0, 0); \
    __builtin_amdgcn_global_load_lds( \
      (const __attribute__((address_space(1))) void*)(Bsrc + (size_t)row_*ldB + (T_)*32 + sc_*8), \
      (__attribute__((address_space(3))) void*)(Bs + ub), 16, 0, 0); \
  } }

  STG(0, 0) STG(1, 1) STG(2, 2)   // 12 vmem instrs in flight

  for (int t=0; t<nt; ++t){
    if (t+2 < nt)      asm volatile("s_waitcnt vmcnt(8)" ::: "memory");
    else if (t+1 < nt) asm volatile("s_waitcnt vmcnt(4)" ::: "memory");
    else               asm volatile("s_waitcnt vmcnt(0)" ::: "memory");
    __builtin_amdgcn_s_barrier();
    if (t+3 < nt) STG((t+3)&3, t+3)
    const int sb = t&3;
    bf16x8 af[8], bq[4];
#pragma unroll
    for (int mi=0;mi<8;mi++)
      af[mi] = *(const bf16x8*)(As + sb*8192 + (wr*128 + mi*16 + l16)*32 + rdc);
#pragma unroll
    for (int ni=0;ni<4;ni++)
      bq[ni] = *(const bf16x8*)(Bs + sb*8192 + (wc*64 + ni*16 + l16)*32 + rdc);
    __builtin_amdgcn_s_setprio(1);
#pragma unroll
    for (int mi=0;mi<8;mi++)
#pragma unroll
      for (int ni=0;ni<4;ni++)
        acc[mi][ni] = MFMA16(af[mi], bq[ni], acc[mi][ni]);
    __builtin_amdgcn_s_setprio(0);
  }
#undef STG
}

// ---------------- fused QKV (Q pre-scaled) ----------------
// grid 576 1D; chunk 72 = 8 bm x 9 bn per XCD (bm-major: same-A blocks colocated)
__global__ __launch_bounds__(512,1) void k8_qkv(
    const __bf16* __restrict__ A, const __bf16* __restrict__ W,
    const float* __restrict__ bq, const float* __restrict__ bk, const float* __restrict__ bv,
    __bf16* __restrict__ Cq, __bf16* __restrict__ Ck, __bf16* __restrict__ Cv)
{
  const int L = xcd_remap(blockIdx.x, 72);
  const int bm = L/9, bn = L%9;
  f32x4 acc[8][4];
  gemm_core_q4(A + (size_t)bm*256*D_MODEL, D_MODEL, W + (size_t)bn*256*D_MODEL, D_MODEL, 24, acc);
  const int tid = threadIdx.x, w=tid>>6, lane=tid&63;
  const int wr=w>>2, wc=w&3, l16=lane&15, l4=lane>>4;
  const int seg = (bn*256)/D_MODEL;
  const int colb = bn*256 - seg*D_MODEL + wc*64;
  const float* bias = seg==0?bq:(seg==1?bk:bv);
  __bf16* C = seg==0?Cq:(seg==1?Ck:Cv);
  const int row0 = bm*256 + wr*128;
#pragma unroll
  for (int ni=0;ni<4;ni++){
    const int col = colb + ni*16 + l16;
    const float bb = bias[col];
#pragma unroll
    for (int mi=0;mi<8;mi++)
#pragma unroll
      for (int r=0;r<4;r++){
        const int row = row0 + mi*16 + l4*4 + r;
        float v = acc[mi][ni][r] + bb;
        if (seg==0) v *= SCALE;
        C[(size_t)row*D_MODEL + col] = (__bf16)v;
      }
  }
}

// ---------------- S = Qs @ K^T (fp16 out) ----------------
// grid 512 1D; chunk 64 = one batch (8 bm x 8 bn, bm-major: K panel L2-resident)
__global__ __launch_bounds__(512,1) void k8_s(
    const __bf16* __restrict__ Q, const __bf16* __restrict__ K, _Float16* __restrict__ S,
    int nb)
{
  const int L = xcd_remap(blockIdx.x, nb*8);
  const int batch = L>>6, r = L&63;
  const int bm = r>>3, bn = r&7;
  const size_t bo = (size_t)batch * SEQLEN * D_MODEL;
  f32x4 acc[8][4];
  gemm_core_q4(Q + bo + (size_t)bm*256*D_MODEL, D_MODEL, K + bo + (size_t)bn*256*D_MODEL, D_MODEL, 24, acc);
  const int tid = threadIdx.x, w=tid>>6, lane=tid&63;
  const int wr=w>>2, wc=w&3, l16=lane&15, l4=lane>>4;
  _Float16* Sb = S + (size_t)batch*SEQLEN*SEQLEN;
  const int row0 = bm*256 + wr*128, col0 = bn*256 + wc*64;
#pragma unroll
  for (int ni=0;ni<4;ni++){
    const int col = col0 + ni*16 + l16;
#pragma unroll
    for (int mi=0;mi<8;mi++)
#pragma unroll
      for (int r2=0;r2<4;r2++)
        Sb[(size_t)(row0 + mi*16 + l4*4 + r2)*SEQLEN + col] = (_Float16)acc[mi][ni][r2];
  }
}

// ---------------- O = P @ V + x (fp32 out) ----------------
// grid 192 1D; chunk 24 = one batch (8 bm x 3 bn; V panels 3MB L2-resident)
__global__ __launch_bounds__(512,1) void k8_pv(
    const __bf16* __restrict__ P, const __bf16* __restrict__ VT,
    const float* __restrict__ x, float* __restrict__ x2, int bbase, int nb)
{
  const int L = xcd_remap(blockIdx.x, nb*3);
  const int by = L/24, r = L%24;
  const int bm = r/3, bn = r%3;
  const int bidx = bbase + by;
  f32x4 acc[8][4];
  gemm_core_q4(P + (size_t)by*SEQLEN*SEQLEN + (size_t)bm*256*SEQLEN, SEQLEN,
               VT + (size_t)bidx*D_MODEL*SEQLEN + (size_t)bn*256*SEQLEN, SEQLEN, 64, acc);
  const int tid = threadIdx.x, w=tid>>6, lane=tid&63;
  const int wr=w>>2, wc=w&3, l16=lane&15, l4=lane>>4;
  const size_t row0 = (size_t)bidx*SEQLEN + bm*256 + wr*128;
  const int col0 = bn*256 + wc*64;
#pragma unroll
  for (int ni=0;ni<4;ni++){
    const int col = col0 + ni*16 + l16;
#pragma unroll
    for (int mi=0;mi<8;mi++)
#pragma unroll
      for (int r2=0;r2<4;r2++){
        const size_t row = row0 + mi*16 + l4*4 + r2;
        x2[row*D_MODEL + col] = acc[mi][ni][r2] + x[row*D_MODEL + col];
      }
  }
}

// ---------------- MLP GEMM: RES=0 bf16+GELU, RES=1 f32+GELU+resid ----------------
// grid 192 1D; chunk 24 = 8 bm x 3 bn (bm-major; W1/W2 1.2MB L2-resident)
template<int RES>
__global__ __launch_bounds__(512,1) void k8_mlp(
    const __bf16* __restrict__ A, const __bf16* __restrict__ W,
    const float* __restrict__ bias, const float* __restrict__ resid, void* __restrict__ out)
{
  const int L = xcd_remap(blockIdx.x, 24);
  const int bm = L/3, bn = L%3;
  f32x4 acc[8][4];
  gemm_core_q4(A + (size_t)bm*256*D_MODEL, D_MODEL, W + (size_t)bn*256*D_MODEL, D_MODEL, 24, acc);
  const int tid = threadIdx.x, w=tid>>6, lane=tid&63;
  const int wr=w>>2, wc=w&3, l16=lane&15, l4=lane>>4;
  const int row0 = bm*256 + wr*128, col0 = bn*256 + wc*64;
#pragma unroll
  for (int ni=0;ni<4;ni++){
    const int col = col0 + ni*16 + l16;
    const float bb = bias[col];
#pragma unroll
    for (int mi=0;mi<8;mi++)
#pragma unroll
      for (int r=0;r<4;r++){
        const int row = row0 + mi*16 + l4*4 + r;
        float v = gelu_exact(acc[mi][ni][r] + bb);
        if (RES) ((float*)out)[(size_t)row*D_MODEL + col] = v + resid[(size_t)row*D_MODEL + col];
        else     ((__bf16*)out)[(size_t)row*D_MODEL + col] = (__bf16)v;
      }
  }
}

// ---------------- launch ----------------
extern "C" void kernel_launch(void* const* d_in, const int* in_sizes, int n_in,
                              void* d_out, int out_size, void* d_ws, size_t ws_size,
                              hipStream_t stream)
{
  const float* x   = (const float*)d_in[0];
  const float* Wq  = (const float*)d_in[1];
  const float* bq  = (const float*)d_in[2];
  const float* Wk  = (const float*)d_in[3];
  const float* bk  = (const float*)d_in[4];
  const float* Wv  = (const float*)d_in[5];
  const float* bv  = (const float*)d_in[6];
  const float* W1  = (const float*)d_in[7];
  const float* b1  = (const float*)d_in[8];
  const float* W2  = (const float*)d_in[9];
  const float* b2  = (const float*)d_in[10];
  const float* g1  = (const float*)d_in[11];
  const float* be1 = (const float*)d_in[12];
  const float* g2  = (const float*)d_in[13];
  const float* be2 = (const float*)d_in[14];
  (void)in_sizes; (void)n_in; (void)out_size;

  char* ws = (char*)d_ws;
  __bf16*   qb  = (__bf16*)(ws + OFF_Q);
  __bf16*   kb  = (__bf16*)(ws + OFF_K);
  __bf16*   vT  = (__bf16*)(ws + OFF_VT);
  float*    x2  = (float*)(ws + OFF_X2);
  __bf16*   wbf = (__bf16*)(ws + OFF_W);
  __bf16*   h1  = (__bf16*)(ws + OFF_POOL);
  __bf16*   vb  = (__bf16*)(ws + OFF_POOL + SZ_ACT);
  _Float16* Sp  = (_Float16*)(ws + OFF_POOL);
  __bf16*   h2  = h1;
  __bf16*   h3  = qb;

  const bool big = ws_size >= OFF_POOL + (size_t)NBATCH*SEQLEN*SEQLEN*2;

  k_cvt5<<<dim3(576,5,1),256,0,stream>>>(Wq,Wk,Wv,W1,W2,wbf);
  k_layernorm<<<dim3(4096),256,0,stream>>>(x, g1, be1, h1);
  k8_qkv<<<dim3(576),512,0,stream>>>(h1, wbf, bq, bk, bv, qb, kb, vb);
  k_transpose_v<<<dim3(32,12,8),256,0,stream>>>(vb, vT);

  if (big){
    k8_s<<<dim3(512),512,0,stream>>>(qb, kb, Sp, 8);
    k_softmax<<<dim3(4096),256,0,stream>>>(Sp);
    k8_pv<<<dim3(192),512,0,stream>>>((const __bf16*)Sp, vT, x, x2, 0, 8);
  } else {
    for (int c=0;c<2;c++){
      const size_t qoff = (size_t)c*4*SEQLEN*D_MODEL;
      k8_s<<<dim3(256),512,0,stream>>>(qb + qoff, kb + qoff, Sp, 4);
      k_softmax<<<dim3(2048),256,0,stream>>>(Sp);
      k8_pv<<<dim3(96),512,0,stream>>>((const __bf16*)Sp, vT, x, x2, c*4, 4);
    }
  }

  k_layernorm<<<dim3(4096),256,0,stream>>>(x2, g2, be2, h2);
  k8_mlp<0><<<dim3(192),512,0,stream>>>(h2, wbf + (size_t)3*589824, b1, nullptr, h3);
  k8_mlp<1><<<dim3(192),512,0,stream>>>(h3, wbf + (size_t)4*589824, b2, x2, d_out);
}

// Round 10
// 399.276 us; speedup vs baseline: 1.2955x; 1.2033x over previous
//
#include <hip/hip_runtime.h>
#include <cstdint>
#include <cstddef>

#define D_MODEL 768
#define NBATCH 8
#define SEQLEN 2048
#define NROWS (NBATCH*SEQLEN)   // 16384

typedef __attribute__((ext_vector_type(4))) float  f32x4;
typedef __attribute__((ext_vector_type(8))) __bf16 bf16x8;
typedef __attribute__((ext_vector_type(4))) __bf16 bf16x4;
typedef __attribute__((ext_vector_type(8))) _Float16 f16x8;

#define MFMA16(a,b,c) __builtin_amdgcn_mfma_f32_16x16x32_bf16(a,b,c,0,0,0)
#define SCALE 0.03608439182435161f   // 1/sqrt(768)
#define AS1 __attribute__((address_space(1)))
#define AS3 __attribute__((address_space(3)))

// ---------------- workspace layout (bytes) ----------------
static constexpr size_t SZ_ACT = (size_t)NROWS * D_MODEL * 2;       // 25165824
static constexpr size_t OFF_Q    = 0;
static constexpr size_t OFF_K    = OFF_Q + SZ_ACT;
static constexpr size_t OFF_VT   = OFF_K + SZ_ACT;
static constexpr size_t OFF_X2   = OFF_VT + SZ_ACT;                 // fp32
static constexpr size_t OFF_W    = OFF_X2 + (size_t)NROWS*D_MODEL*4;
static constexpr size_t OFF_POOL = OFF_W + (size_t)5*589824*2;      // 131727360

__device__ __forceinline__ float gelu_exact(float x) {
  return 0.5f * x * (1.0f + erff(x * 0.70710678118654752f));
}

// bijective XCD chunk remap (grid divisible by 8): physical p -> logical L
__device__ __forceinline__ int xcd_remap(int p, int chunk) {
  return (p & 7) * chunk + (p >> 3);
}

// ---------------- weight fp32 -> bf16 ----------------
__global__ __launch_bounds__(256) void k_cvt5(
    const float* __restrict__ s0, const float* __restrict__ s1,
    const float* __restrict__ s2, const float* __restrict__ s3,
    const float* __restrict__ s4, __bf16* __restrict__ dst)
{
  const int wsel = blockIdx.y;
  const float* s = wsel==0 ? s0 : wsel==1 ? s1 : wsel==2 ? s2 : wsel==3 ? s3 : s4;
  const size_t i = ((size_t)blockIdx.x*256 + threadIdx.x)*4;
  float4 v = *(const float4*)(s + i);
  bf16x4 o;
  o[0] = (__bf16)v.x; o[1] = (__bf16)v.y; o[2] = (__bf16)v.z; o[3] = (__bf16)v.w;
  *(bf16x4*)(dst + (size_t)wsel*589824 + i) = o;
}

// ---------------- LayerNorm (wave per row) ----------------
__global__ __launch_bounds__(256) void k_layernorm(
    const float* __restrict__ x, const float* __restrict__ g,
    const float* __restrict__ be, __bf16* __restrict__ out)
{
  const int row  = blockIdx.x*4 + (threadIdx.x>>6);
  const int lane = threadIdx.x & 63;
  const float4* xr = (const float4*)(x + (size_t)row*D_MODEL);
  float4 v[3];
  float s = 0.f, ss = 0.f;
#pragma unroll
  for (int j=0;j<3;j++){
    v[j] = xr[lane + 64*j];
    s  += v[j].x + v[j].y + v[j].z + v[j].w;
    ss += v[j].x*v[j].x + v[j].y*v[j].y + v[j].z*v[j].z + v[j].w*v[j].w;
  }
#pragma unroll
  for (int d=1; d<64; d<<=1){ s += __shfl_xor(s,d); ss += __shfl_xor(ss,d); }
  const float mu   = s  * (1.f/768.f);
  const float var  = ss * (1.f/768.f) - mu*mu;
  const float rstd = rsqrtf(var + 1e-5f);
  __bf16* orow = out + (size_t)row*D_MODEL;
#pragma unroll
  for (int j=0;j<3;j++){
    const int c0 = (lane + 64*j)*4;
    bf16x4 o;
    o[0] = (__bf16)((v[j].x - mu)*rstd*g[c0+0] + be[c0+0]);
    o[1] = (__bf16)((v[j].y - mu)*rstd*g[c0+1] + be[c0+1]);
    o[2] = (__bf16)((v[j].z - mu)*rstd*g[c0+2] + be[c0+2]);
    o[3] = (__bf16)((v[j].w - mu)*rstd*g[c0+3] + be[c0+3]);
    *(bf16x4*)(orow + c0) = o;
  }
}

// ---------------- V transpose: v[b,t,d] -> vT[b,d,t] ----------------
__global__ __launch_bounds__(256) void k_transpose_v(
    const __bf16* __restrict__ v, __bf16* __restrict__ vT)
{
  __shared__ __bf16 tile[64][72];
  const int b = blockIdx.z;
  const int t0 = blockIdx.x*64, d0 = blockIdx.y*64;
  const int tid = threadIdx.x;
  const int rr = (tid>>3)*2, cc = (tid&7)*8;
  const __bf16* src = v + ((size_t)b*SEQLEN + t0)*D_MODEL + d0;
#pragma unroll
  for (int j=0;j<2;j++){
    bf16x8 val = *(const bf16x8*)(src + (size_t)(rr+j)*D_MODEL + cc);
#pragma unroll
    for (int e=0;e<8;e++) tile[cc+e][rr+j] = val[e];
  }
  __syncthreads();
  __bf16* dst = vT + ((size_t)b*D_MODEL + d0)*SEQLEN + t0;
#pragma unroll
  for (int j=0;j<2;j++){
    bf16x8 o;
#pragma unroll
    for (int e=0;e<8;e++) o[e] = tile[rr+j][cc+e];
    *(bf16x8*)(dst + (size_t)(rr+j)*SEQLEN + cc) = o;
  }
}

// ---------------- row softmax, in-place fp16 -> bf16 ----------------
__global__ __launch_bounds__(256) void k_softmax(_Float16* __restrict__ S)
{
  const int row  = blockIdx.x*4 + (threadIdx.x>>6);
  const int lane = threadIdx.x & 63;
  _Float16* sr = S + (size_t)row*SEQLEN + lane*32;
  f16x8 v[4];
#pragma unroll
  for (int j=0;j<4;j++) v[j] = *(const f16x8*)(sr + j*8);
  float f[32];
  float mx = -1e30f;
#pragma unroll
  for (int j=0;j<4;j++)
#pragma unroll
    for (int e=0;e<8;e++){ f[j*8+e] = (float)v[j][e]; mx = fmaxf(mx, f[j*8+e]); }
#pragma unroll
  for (int d=1; d<64; d<<=1) mx = fmaxf(mx, __shfl_xor(mx, d));
  float sum = 0.f;
#pragma unroll
  for (int i=0;i<32;i++){ f[i] = __expf(f[i]-mx); sum += f[i]; }
#pragma unroll
  for (int d=1; d<64; d<<=1) sum += __shfl_xor(sum, d);
  const float inv = 1.f/sum;
  __bf16* pr = (__bf16*)(S + (size_t)row*SEQLEN) + lane*32;
#pragma unroll
  for (int j=0;j<4;j++){
    bf16x8 o;
#pragma unroll
    for (int e=0;e<8;e++) o[e] = (__bf16)(f[j*8+e]*inv);
    *(bf16x8*)(pr + j*8) = o;
  }
}

// =====================================================================
// 128x128 NT GEMM core, BK=32, 4 waves (2x2), TRIPLE-buffered LDS (48KB
// -> 3 blocks/CU = 12 waves/CU), counted vmcnt (stage t+2 during t,
// boundary wait vmcnt(4) = 2-tile lead), full XOR swizzle
// s(row)=(row^(row>>2))&3 on both store-source and read (rule #21)
// -> 2-way max bank aliasing (free). Two barriers/tile:
//   vmcnt(4); bar; ds_read x8; lgkmcnt(0); bar; stage(t+2); MFMA x16.
// Race-safety: buf[(t+2)%3] was last READ at tile t-1, whose reads
// completed before its own lgkmcnt+barrier (globally before this stage).
// acc[mi][ni][r]: row = wr*64+mi*16+l4*4+r, col = wc*64+ni*16+l16.
// =====================================================================
template<int NT>
__device__ __forceinline__ void gemm_core_t3(
    const __bf16* __restrict__ Asrc, const int ldA,
    const __bf16* __restrict__ Bsrc, const int ldB,
    f32x4 (&acc)[4][4])
{
  __shared__ __bf16 As[3*4096];   // 3 bufs x 128 rows x 32 elems
  __shared__ __bf16 Bs[3*4096];
  const int tid = threadIdx.x, w = tid>>6, lane = tid&63;
  const int wr = w>>1, wc = w&1, l16 = lane&15, l4 = lane>>4;
  const int rs  = (l16 ^ (l16>>2)) & 3;          // s(row) for frag rows (row%16 == l16)
  const int rdo = (l4 ^ rs) * 8;                 // swizzled read offset (elems)
  const int srl = lane>>2;                       // staging sub-row (0..15)
  const int ssw = (((lane&3) ^ ((srl ^ (srl>>2)) & 3))) * 8;   // staging src chunk offset

#pragma unroll
  for (int mi=0;mi<4;mi++)
#pragma unroll
    for (int ni=0;ni<4;ni++)
      acc[mi][ni] = (f32x4){0.f,0.f,0.f,0.f};

  // stage tile T_: per wave 2 A-instrs + 2 B-instrs (1KB each, linear LDS
  // dest; global source column inverse-swizzled per lane).
#define STG3(T_) { \
    const int kb_ = (T_)*32; \
    const int sb_ = ((T_)%3)*4096; \
    _Pragma("unroll") \
    for (int i_=0;i_<2;i_++){ \
      const int ii_ = w + i_*4; \
      const int rl_ = ii_*16 + srl; \
      __builtin_amdgcn_global_load_lds((const AS1 void*)(Asrc + (size_t)rl_*ldA + kb_ + ssw), (AS3 void*)(As + sb_ + ii_*512), 16, 0, 0); \
      __builtin_amdgcn_global_load_lds((const AS1 void*)(Bsrc + (size_t)rl_*ldB + kb_ + ssw), (AS3 void*)(Bs + sb_ + ii_*512), 16, 0, 0); \
    } }

  STG3(0) STG3(1)

  for (int t=0; t<NT; ++t){
    if (t+1 < NT) asm volatile("s_waitcnt vmcnt(4)" ::: "memory");
    else          asm volatile("s_waitcnt vmcnt(0)" ::: "memory");
    __builtin_amdgcn_s_barrier();
    const int sb = (t%3)*4096;
    bf16x8 af[4], bq[4];
#pragma unroll
    for (int mi=0;mi<4;mi++)
      af[mi] = *(const bf16x8*)(As + sb + (wr*64 + mi*16 + l16)*32 + rdo);
#pragma unroll
    for (int ni=0;ni<4;ni++)
      bq[ni] = *(const bf16x8*)(Bs + sb + (wc*64 + ni*16 + l16)*32 + rdo);
    asm volatile("s_waitcnt lgkmcnt(0)" ::: "memory");
    __builtin_amdgcn_sched_barrier(0);
    __builtin_amdgcn_s_barrier();
    if (t+2 < NT) STG3(t+2)
    __builtin_amdgcn_s_setprio(1);
#pragma unroll
    for (int mi=0;mi<4;mi++)
#pragma unroll
      for (int ni=0;ni<4;ni++)
        acc[mi][ni] = MFMA16(af[mi], bq[ni], acc[mi][ni]);
    __builtin_amdgcn_s_setprio(0);
  }
#undef STG3
}

// ---------------- fused QKV (Q pre-scaled): grid 2304, chunk 288 ----------------
__global__ __launch_bounds__(256) void k_qkv(
    const __bf16* __restrict__ A, const __bf16* __restrict__ W,
    const float* __restrict__ bq, const float* __restrict__ bk, const float* __restrict__ bv,
    __bf16* __restrict__ Cq, __bf16* __restrict__ Ck, __bf16* __restrict__ Cv)
{
  const int L = xcd_remap(blockIdx.x, 288);
  const int bm = L/18, bn = L%18;
  f32x4 acc[4][4];
  gemm_core_t3<24>(A + (size_t)bm*128*D_MODEL, D_MODEL, W + (size_t)bn*128*D_MODEL, D_MODEL, acc);
  const int tid = threadIdx.x, w=tid>>6, lane=tid&63;
  const int wr=w>>1, wc=w&1, l16=lane&15, l4=lane>>4;
  const int seg = bn/6;
  const int colb = (bn%6)*128 + wc*64;
  const float* bias = seg==0?bq:(seg==1?bk:bv);
  __bf16* C = seg==0?Cq:(seg==1?Ck:Cv);
  const int row0 = bm*128 + wr*64;
#pragma unroll
  for (int ni=0;ni<4;ni++){
    const int col = colb + ni*16 + l16;
    const float bb = bias[col];
#pragma unroll
    for (int mi=0;mi<4;mi++)
#pragma unroll
      for (int r=0;r<4;r++){
        const int row = row0 + mi*16 + l4*4 + r;
        float v = acc[mi][ni][r] + bb;
        if (seg==0) v *= SCALE;
        C[(size_t)row*D_MODEL + col] = (__bf16)v;
      }
  }
}

// ---------------- S = Qs @ K^T (fp16 out): grid nb*256, chunk nb*32 ----------------
__global__ __launch_bounds__(256) void k_s(
    const __bf16* __restrict__ Q, const __bf16* __restrict__ K, _Float16* __restrict__ S,
    int chunk)
{
  const int L = xcd_remap(blockIdx.x, chunk);
  const int batch = L>>8, r = L&255;
  const int bm = r>>4, bn = r&15;
  const size_t bo = (size_t)batch * SEQLEN * D_MODEL;
  f32x4 acc[4][4];
  gemm_core_t3<24>(Q + bo + (size_t)bm*128*D_MODEL, D_MODEL, K + bo + (size_t)bn*128*D_MODEL, D_MODEL, acc);
  const int tid = threadIdx.x, w=tid>>6, lane=tid&63;
  const int wr=w>>1, wc=w&1, l16=lane&15, l4=lane>>4;
  _Float16* Sb = S + (size_t)batch*SEQLEN*SEQLEN;
  const int row0 = bm*128 + wr*64, col0 = bn*128 + wc*64;
#pragma unroll
  for (int ni=0;ni<4;ni++){
    const int col = col0 + ni*16 + l16;
#pragma unroll
    for (int mi=0;mi<4;mi++)
#pragma unroll
      for (int r2=0;r2<4;r2++)
        Sb[(size_t)(row0 + mi*16 + l4*4 + r2)*SEQLEN + col] = (_Float16)acc[mi][ni][r2];
  }
}

// ---------------- O = P @ V + x (fp32 out): grid nb*96, chunk nb*12 ----------------
__global__ __launch_bounds__(256) void k_pv(
    const __bf16* __restrict__ P, const __bf16* __restrict__ VT,
    const float* __restrict__ x, float* __restrict__ x2, int bbase, int chunk)
{
  const int L = xcd_remap(blockIdx.x, chunk);
  const int by = L/96, r = L%96;
  const int bm = r/6, bn = r%6;
  const int bidx = bbase + by;
  f32x4 acc[4][4];
  gemm_core_t3<64>(P + (size_t)by*SEQLEN*SEQLEN + (size_t)bm*128*SEQLEN, SEQLEN,
                   VT + (size_t)bidx*D_MODEL*SEQLEN + (size_t)bn*128*SEQLEN, SEQLEN, acc);
  const int tid = threadIdx.x, w=tid>>6, lane=tid&63;
  const int wr=w>>1, wc=w&1, l16=lane&15, l4=lane>>4;
  const size_t row0 = (size_t)bidx*SEQLEN + bm*128 + wr*64;
  const int col0 = bn*128 + wc*64;
#pragma unroll
  for (int ni=0;ni<4;ni++){
    const int col = col0 + ni*16 + l16;
#pragma unroll
    for (int mi=0;mi<4;mi++)
#pragma unroll
      for (int r2=0;r2<4;r2++){
        const size_t row = row0 + mi*16 + l4*4 + r2;
        x2[row*D_MODEL + col] = acc[mi][ni][r2] + x[row*D_MODEL + col];
      }
  }
}

// ---------------- MLP GEMM: grid 768, chunk 96 ----------------
template<int RES>
__global__ __launch_bounds__(256) void k_mlp(
    const __bf16* __restrict__ A, const __bf16* __restrict__ W,
    const float* __restrict__ bias, const float* __restrict__ resid, void* __restrict__ out)
{
  const int L = xcd_remap(blockIdx.x, 96);
  const int bm = L/6, bn = L%6;
  f32x4 acc[4][4];
  gemm_core_t3<24>(A + (size_t)bm*128*D_MODEL, D_MODEL, W + (size_t)bn*128*D_MODEL, D_MODEL, acc);
  const int tid = threadIdx.x, w=tid>>6, lane=tid&63;
  const int wr=w>>1, wc=w&1, l16=lane&15, l4=lane>>4;
  const int row0 = bm*128 + wr*64, col0 = bn*128 + wc*64;
#pragma unroll
  for (int ni=0;ni<4;ni++){
    const int col = col0 + ni*16 + l16;
    const float bb = bias[col];
#pragma unroll
    for (int mi=0;mi<4;mi++)
#pragma unroll
      for (int r=0;r<4;r++){
        const int row = row0 + mi*16 + l4*4 + r;
        float v = gelu_exact(acc[mi][ni][r] + bb);
        if (RES) ((float*)out)[(size_t)row*D_MODEL + col] = v + resid[(size_t)row*D_MODEL + col];
        else     ((__bf16*)out)[(size_t)row*D_MODEL + col] = (__bf16)v;
      }
  }
}

// ---------------- launch ----------------
extern "C" void kernel_launch(void* const* d_in, const int* in_sizes, int n_in,
                              void* d_out, int out_size, void* d_ws, size_t ws_size,
                              hipStream_t stream)
{
  const float* x   = (const float*)d_in[0];
  const float* Wq  = (const float*)d_in[1];
  const float* bq  = (const float*)d_in[2];
  const float* Wk  = (const float*)d_in[3];
  const float* bk  = (const float*)d_in[4];
  const float* Wv  = (const float*)d_in[5];
  const float* bv  = (const float*)d_in[6];
  const float* W1  = (const float*)d_in[7];
  const float* b1  = (const float*)d_in[8];
  const float* W2  = (const float*)d_in[9];
  const float* b2  = (const float*)d_in[10];
  const float* g1  = (const float*)d_in[11];
  const float* be1 = (const float*)d_in[12];
  const float* g2  = (const float*)d_in[13];
  const float* be2 = (const float*)d_in[14];
  (void)in_sizes; (void)n_in; (void)out_size;

  char* ws = (char*)d_ws;
  __bf16*   qb  = (__bf16*)(ws + OFF_Q);
  __bf16*   kb  = (__bf16*)(ws + OFF_K);
  __bf16*   vT  = (__bf16*)(ws + OFF_VT);
  float*    x2  = (float*)(ws + OFF_X2);
  __bf16*   wbf = (__bf16*)(ws + OFF_W);
  __bf16*   h1  = (__bf16*)(ws + OFF_POOL);
  __bf16*   vb  = (__bf16*)(ws + OFF_POOL + SZ_ACT);
  _Float16* Sp  = (_Float16*)(ws + OFF_POOL);
  __bf16*   h2  = h1;
  __bf16*   h3  = qb;

  const bool big = ws_size >= OFF_POOL + (size_t)NBATCH*SEQLEN*SEQLEN*2;

  k_cvt5<<<dim3(576,5,1),256,0,stream>>>(Wq,Wk,Wv,W1,W2,wbf);
  k_layernorm<<<dim3(4096),256,0,stream>>>(x, g1, be1, h1);
  k_qkv<<<dim3(2304),256,0,stream>>>(h1, wbf, bq, bk, bv, qb, kb, vb);
  k_transpose_v<<<dim3(32,12,8),256,0,stream>>>(vb, vT);

  if (big){
    k_s<<<dim3(2048),256,0,stream>>>(qb, kb, Sp, 256);
    k_softmax<<<dim3(4096),256,0,stream>>>(Sp);
    k_pv<<<dim3(768),256,0,stream>>>((const __bf16*)Sp, vT, x, x2, 0, 96);
  } else {
    for (int c=0;c<2;c++){
      const size_t qoff = (size_t)c*4*SEQLEN*D_MODEL;
      k_s<<<dim3(1024),256,0,stream>>>(qb + qoff, kb + qoff, Sp, 128);
      k_softmax<<<dim3(2048),256,0,stream>>>(Sp);
      k_pv<<<dim3(384),256,0,stream>>>((const __bf16*)Sp, vT, x, x2, c*4, 48);
    }
  }

  k_layernorm<<<dim3(4096),256,0,stream>>>(x2, g2, be2, h2);
  k_mlp<0><<<dim3(768),256,0,stream>>>(h2, wbf + (size_t)3*589824, b1, nullptr, h3);
  k_mlp<1><<<dim3(768),256,0,stream>>>(h3, wbf + (size_t)4*589824, b2, x2, d_out);
}

// Round 11
// 393.578 us; speedup vs baseline: 1.3142x; 1.0145x over previous
//
#include <hip/hip_runtime.h>
#include <cstdint>
#include <cstddef>

#define D_MODEL 768
#define NBATCH 8
#define SEQLEN 2048
#define NROWS (NBATCH*SEQLEN)   // 16384

typedef __attribute__((ext_vector_type(4))) float  f32x4;
typedef __attribute__((ext_vector_type(8))) __bf16 bf16x8;
typedef __attribute__((ext_vector_type(4))) __bf16 bf16x4;
typedef __attribute__((ext_vector_type(8))) _Float16 f16x8;

#define MFMA16(a,b,c) __builtin_amdgcn_mfma_f32_16x16x32_bf16(a,b,c,0,0,0)
#define SCALE 0.03608439182435161f   // 1/sqrt(768)
#define AS1 __attribute__((address_space(1)))
#define AS3 __attribute__((address_space(3)))

// ---------------- workspace layout (bytes) ----------------
static constexpr size_t SZ_ACT = (size_t)NROWS * D_MODEL * 2;       // 25165824
static constexpr size_t OFF_Q    = 0;
static constexpr size_t OFF_K    = OFF_Q + SZ_ACT;
static constexpr size_t OFF_VT   = OFF_K + SZ_ACT;
static constexpr size_t OFF_X2   = OFF_VT + SZ_ACT;                 // fp32
static constexpr size_t OFF_W    = OFF_X2 + (size_t)NROWS*D_MODEL*4;
static constexpr size_t OFF_POOL = OFF_W + (size_t)5*589824*2;      // 131727360

__device__ __forceinline__ float gelu_exact(float x) {
  return 0.5f * x * (1.0f + erff(x * 0.70710678118654752f));
}

// bijective XCD chunk remap (grid divisible by 8): physical p -> logical L
__device__ __forceinline__ int xcd_remap(int p, int chunk) {
  return (p & 7) * chunk + (p >> 3);
}

// ---------------- weight fp32 -> bf16 ----------------
__global__ __launch_bounds__(256) void k_cvt5(
    const float* __restrict__ s0, const float* __restrict__ s1,
    const float* __restrict__ s2, const float* __restrict__ s3,
    const float* __restrict__ s4, __bf16* __restrict__ dst)
{
  const int wsel = blockIdx.y;
  const float* s = wsel==0 ? s0 : wsel==1 ? s1 : wsel==2 ? s2 : wsel==3 ? s3 : s4;
  const size_t i = ((size_t)blockIdx.x*256 + threadIdx.x)*4;
  float4 v = *(const float4*)(s + i);
  bf16x4 o;
  o[0] = (__bf16)v.x; o[1] = (__bf16)v.y; o[2] = (__bf16)v.z; o[3] = (__bf16)v.w;
  *(bf16x4*)(dst + (size_t)wsel*589824 + i) = o;
}

// ---------------- LayerNorm (wave per row) ----------------
__global__ __launch_bounds__(256) void k_layernorm(
    const float* __restrict__ x, const float* __restrict__ g,
    const float* __restrict__ be, __bf16* __restrict__ out)
{
  const int row  = blockIdx.x*4 + (threadIdx.x>>6);
  const int lane = threadIdx.x & 63;
  const float4* xr = (const float4*)(x + (size_t)row*D_MODEL);
  float4 v[3];
  float s = 0.f, ss = 0.f;
#pragma unroll
  for (int j=0;j<3;j++){
    v[j] = xr[lane + 64*j];
    s  += v[j].x + v[j].y + v[j].z + v[j].w;
    ss += v[j].x*v[j].x + v[j].y*v[j].y + v[j].z*v[j].z + v[j].w*v[j].w;
  }
#pragma unroll
  for (int d=1; d<64; d<<=1){ s += __shfl_xor(s,d); ss += __shfl_xor(ss,d); }
  const float mu   = s  * (1.f/768.f);
  const float var  = ss * (1.f/768.f) - mu*mu;
  const float rstd = rsqrtf(var + 1e-5f);
  __bf16* orow = out + (size_t)row*D_MODEL;
#pragma unroll
  for (int j=0;j<3;j++){
    const int c0 = (lane + 64*j)*4;
    bf16x4 o;
    o[0] = (__bf16)((v[j].x - mu)*rstd*g[c0+0] + be[c0+0]);
    o[1] = (__bf16)((v[j].y - mu)*rstd*g[c0+1] + be[c0+1]);
    o[2] = (__bf16)((v[j].z - mu)*rstd*g[c0+2] + be[c0+2]);
    o[3] = (__bf16)((v[j].w - mu)*rstd*g[c0+3] + be[c0+3]);
    *(bf16x4*)(orow + c0) = o;
  }
}

// ---------------- V transpose: v[b,t,d] -> vT[b,d,t] ----------------
__global__ __launch_bounds__(256) void k_transpose_v(
    const __bf16* __restrict__ v, __bf16* __restrict__ vT)
{
  __shared__ __bf16 tile[64][72];
  const int b = blockIdx.z;
  const int t0 = blockIdx.x*64, d0 = blockIdx.y*64;
  const int tid = threadIdx.x;
  const int rr = (tid>>3)*2, cc = (tid&7)*8;
  const __bf16* src = v + ((size_t)b*SEQLEN + t0)*D_MODEL + d0;
#pragma unroll
  for (int j=0;j<2;j++){
    bf16x8 val = *(const bf16x8*)(src + (size_t)(rr+j)*D_MODEL + cc);
#pragma unroll
    for (int e=0;e<8;e++) tile[cc+e][rr+j] = val[e];
  }
  __syncthreads();
  __bf16* dst = vT + ((size_t)b*D_MODEL + d0)*SEQLEN + t0;
#pragma unroll
  for (int j=0;j<2;j++){
    bf16x8 o;
#pragma unroll
    for (int e=0;e<8;e++) o[e] = tile[rr+j][cc+e];
    *(bf16x8*)(dst + (size_t)(rr+j)*SEQLEN + cc) = o;
  }
}

// ---------------- row softmax, in-place fp16 -> bf16 ----------------
__global__ __launch_bounds__(256) void k_softmax(_Float16* __restrict__ S)
{
  const int row  = blockIdx.x*4 + (threadIdx.x>>6);
  const int lane = threadIdx.x & 63;
  _Float16* sr = S + (size_t)row*SEQLEN + lane*32;
  f16x8 v[4];
#pragma unroll
  for (int j=0;j<4;j++) v[j] = *(const f16x8*)(sr + j*8);
  float f[32];
  float mx = -1e30f;
#pragma unroll
  for (int j=0;j<4;j++)
#pragma unroll
    for (int e=0;e<8;e++){ f[j*8+e] = (float)v[j][e]; mx = fmaxf(mx, f[j*8+e]); }
#pragma unroll
  for (int d=1; d<64; d<<=1) mx = fmaxf(mx, __shfl_xor(mx, d));
  float sum = 0.f;
#pragma unroll
  for (int i=0;i<32;i++){ f[i] = __expf(f[i]-mx); sum += f[i]; }
#pragma unroll
  for (int d=1; d<64; d<<=1) sum += __shfl_xor(sum, d);
  const float inv = 1.f/sum;
  __bf16* pr = (__bf16*)(S + (size_t)row*SEQLEN) + lane*32;
#pragma unroll
  for (int j=0;j<4;j++){
    bf16x8 o;
#pragma unroll
    for (int e=0;e<8;e++) o[e] = (__bf16)(f[j*8+e]*inv);
    *(bf16x8*)(pr + j*8) = o;
  }
}

// =====================================================================
// 128x128 NT GEMM core, BK=32, 4 waves (2x2), DOUBLE-buffered LDS (32KB
// -> 5 blocks/CU = 20 waves/CU; VGPR 92 -> 5 waves/SIMD fits 512 budget).
// TLP-first design: latency hiding via 5 independent barrier-groups per
// CU (m114 implicit overlap), not deep per-block pipelining. Counted
// vmcnt(4) at tile top (stage t+1 stays in flight); stage(t+2) into
// buf[t&1] after the read-done barrier (safe: all waves' ds_reads of t
// drained before barrier 2). Same swizzle as r10 (residual ~4-way,
// ~10us total -- accepted this round).
// acc[mi][ni][r]: row = wr*64+mi*16+l4*4+r, col = wc*64+ni*16+l16.
// =====================================================================
template<int NT>
__device__ __forceinline__ void gemm_core_d2(
    const __bf16* __restrict__ Asrc, const int ldA,
    const __bf16* __restrict__ Bsrc, const int ldB,
    f32x4 (&acc)[4][4])
{
  __shared__ __bf16 As[2*4096];   // 2 bufs x 128 rows x 32 elems
  __shared__ __bf16 Bs[2*4096];
  const int tid = threadIdx.x, w = tid>>6, lane = tid&63;
  const int wr = w>>1, wc = w&1, l16 = lane&15, l4 = lane>>4;
  const int rs  = (l16 ^ (l16>>2)) & 3;          // s(row), row%16 == l16
  const int rdo = (l4 ^ rs) * 8;                 // swizzled read offset (elems)
  const int srl = lane>>2;                       // staging sub-row (0..15)
  const int ssw = (((lane&3) ^ ((srl ^ (srl>>2)) & 3))) * 8;   // staging src chunk

#pragma unroll
  for (int mi=0;mi<4;mi++)
#pragma unroll
    for (int ni=0;ni<4;ni++)
      acc[mi][ni] = (f32x4){0.f,0.f,0.f,0.f};

#define STG2(T_) { \
    const int kb_ = (T_)*32; \
    const int sb_ = ((T_)&1)*4096; \
    _Pragma("unroll") \
    for (int i_=0;i_<2;i_++){ \
      const int ii_ = w + i_*4; \
      const int rl_ = ii_*16 + srl; \
      __builtin_amdgcn_global_load_lds((const AS1 void*)(Asrc + (size_t)rl_*ldA + kb_ + ssw), (AS3 void*)(As + sb_ + ii_*512), 16, 0, 0); \
      __builtin_amdgcn_global_load_lds((const AS1 void*)(Bsrc + (size_t)rl_*ldB + kb_ + ssw), (AS3 void*)(Bs + sb_ + ii_*512), 16, 0, 0); \
    } }

  STG2(0) STG2(1)   // 8 vmem in flight

  for (int t=0; t<NT; ++t){
    if (t+1 < NT) asm volatile("s_waitcnt vmcnt(4)" ::: "memory");
    else          asm volatile("s_waitcnt vmcnt(0)" ::: "memory");
    __builtin_amdgcn_s_barrier();
    const int sb = (t&1)*4096;
    bf16x8 af[4], bq[4];
#pragma unroll
    for (int mi=0;mi<4;mi++)
      af[mi] = *(const bf16x8*)(As + sb + (wr*64 + mi*16 + l16)*32 + rdo);
#pragma unroll
    for (int ni=0;ni<4;ni++)
      bq[ni] = *(const bf16x8*)(Bs + sb + (wc*64 + ni*16 + l16)*32 + rdo);
    asm volatile("s_waitcnt lgkmcnt(0)" ::: "memory");
    __builtin_amdgcn_sched_barrier(0);
    __builtin_amdgcn_s_barrier();
    if (t+2 < NT) STG2(t+2)
    __builtin_amdgcn_s_setprio(1);
#pragma unroll
    for (int mi=0;mi<4;mi++)
#pragma unroll
      for (int ni=0;ni<4;ni++)
        acc[mi][ni] = MFMA16(af[mi], bq[ni], acc[mi][ni]);
    __builtin_amdgcn_s_setprio(0);
  }
#undef STG2
}

// ---------------- fused QKV (Q pre-scaled): grid 2304, chunk 288 ----------------
__global__ __launch_bounds__(256) void k_qkv(
    const __bf16* __restrict__ A, const __bf16* __restrict__ W,
    const float* __restrict__ bq, const float* __restrict__ bk, const float* __restrict__ bv,
    __bf16* __restrict__ Cq, __bf16* __restrict__ Ck, __bf16* __restrict__ Cv)
{
  const int L = xcd_remap(blockIdx.x, 288);
  const int bm = L/18, bn = L%18;
  f32x4 acc[4][4];
  gemm_core_d2<24>(A + (size_t)bm*128*D_MODEL, D_MODEL, W + (size_t)bn*128*D_MODEL, D_MODEL, acc);
  const int tid = threadIdx.x, w=tid>>6, lane=tid&63;
  const int wr=w>>1, wc=w&1, l16=lane&15, l4=lane>>4;
  const int seg = bn/6;
  const int colb = (bn%6)*128 + wc*64;
  const float* bias = seg==0?bq:(seg==1?bk:bv);
  __bf16* C = seg==0?Cq:(seg==1?Ck:Cv);
  const int row0 = bm*128 + wr*64;
#pragma unroll
  for (int ni=0;ni<4;ni++){
    const int col = colb + ni*16 + l16;
    const float bb = bias[col];
#pragma unroll
    for (int mi=0;mi<4;mi++)
#pragma unroll
      for (int r=0;r<4;r++){
        const int row = row0 + mi*16 + l4*4 + r;
        float v = acc[mi][ni][r] + bb;
        if (seg==0) v *= SCALE;
        C[(size_t)row*D_MODEL + col] = (__bf16)v;
      }
  }
}

// ---------------- S = Qs @ K^T (fp16 out): grid nb*256, chunk nb*32 ----------------
__global__ __launch_bounds__(256) void k_s(
    const __bf16* __restrict__ Q, const __bf16* __restrict__ K, _Float16* __restrict__ S,
    int chunk)
{
  const int L = xcd_remap(blockIdx.x, chunk);
  const int batch = L>>8, r = L&255;
  const int bm = r>>4, bn = r&15;
  const size_t bo = (size_t)batch * SEQLEN * D_MODEL;
  f32x4 acc[4][4];
  gemm_core_d2<24>(Q + bo + (size_t)bm*128*D_MODEL, D_MODEL, K + bo + (size_t)bn*128*D_MODEL, D_MODEL, acc);
  const int tid = threadIdx.x, w=tid>>6, lane=tid&63;
  const int wr=w>>1, wc=w&1, l16=lane&15, l4=lane>>4;
  _Float16* Sb = S + (size_t)batch*SEQLEN*SEQLEN;
  const int row0 = bm*128 + wr*64, col0 = bn*128 + wc*64;
#pragma unroll
  for (int ni=0;ni<4;ni++){
    const int col = col0 + ni*16 + l16;
#pragma unroll
    for (int mi=0;mi<4;mi++)
#pragma unroll
      for (int r2=0;r2<4;r2++)
        Sb[(size_t)(row0 + mi*16 + l4*4 + r2)*SEQLEN + col] = (_Float16)acc[mi][ni][r2];
  }
}

// ---------------- O = P @ V + x (fp32 out): grid nb*96, chunk nb*12 ----------------
__global__ __launch_bounds__(256) void k_pv(
    const __bf16* __restrict__ P, const __bf16* __restrict__ VT,
    const float* __restrict__ x, float* __restrict__ x2, int bbase, int chunk)
{
  const int L = xcd_remap(blockIdx.x, chunk);
  const int by = L/96, r = L%96;
  const int bm = r/6, bn = r%6;
  const int bidx = bbase + by;
  f32x4 acc[4][4];
  gemm_core_d2<64>(P + (size_t)by*SEQLEN*SEQLEN + (size_t)bm*128*SEQLEN, SEQLEN,
                   VT + (size_t)bidx*D_MODEL*SEQLEN + (size_t)bn*128*SEQLEN, SEQLEN, acc);
  const int tid = threadIdx.x, w=tid>>6, lane=tid&63;
  const int wr=w>>1, wc=w&1, l16=lane&15, l4=lane>>4;
  const size_t row0 = (size_t)bidx*SEQLEN + bm*128 + wr*64;
  const int col0 = bn*128 + wc*64;
#pragma unroll
  for (int ni=0;ni<4;ni++){
    const int col = col0 + ni*16 + l16;
#pragma unroll
    for (int mi=0;mi<4;mi++)
#pragma unroll
      for (int r2=0;r2<4;r2++){
        const size_t row = row0 + mi*16 + l4*4 + r2;
        x2[row*D_MODEL + col] = acc[mi][ni][r2] + x[row*D_MODEL + col];
      }
  }
}

// ---------------- MLP GEMM: grid 768, chunk 96 ----------------
template<int RES>
__global__ __launch_bounds__(256) void k_mlp(
    const __bf16* __restrict__ A, const __bf16* __restrict__ W,
    const float* __restrict__ bias, const float* __restrict__ resid, void* __restrict__ out)
{
  const int L = xcd_remap(blockIdx.x, 96);
  const int bm = L/6, bn = L%6;
  f32x4 acc[4][4];
  gemm_core_d2<24>(A + (size_t)bm*128*D_MODEL, D_MODEL, W + (size_t)bn*128*D_MODEL, D_MODEL, acc);
  const int tid = threadIdx.x, w=tid>>6, lane=tid&63;
  const int wr=w>>1, wc=w&1, l16=lane&15, l4=lane>>4;
  const int row0 = bm*128 + wr*64, col0 = bn*128 + wc*64;
#pragma unroll
  for (int ni=0;ni<4;ni++){
    const int col = col0 + ni*16 + l16;
    const float bb = bias[col];
#pragma unroll
    for (int mi=0;mi<4;mi++)
#pragma unroll
      for (int r=0;r<4;r++){
        const int row = row0 + mi*16 + l4*4 + r;
        float v = gelu_exact(acc[mi][ni][r] + bb);
        if (RES) ((float*)out)[(size_t)row*D_MODEL + col] = v + resid[(size_t)row*D_MODEL + col];
        else     ((__bf16*)out)[(size_t)row*D_MODEL + col] = (__bf16)v;
      }
  }
}

// ---------------- launch ----------------
extern "C" void kernel_launch(void* const* d_in, const int* in_sizes, int n_in,
                              void* d_out, int out_size, void* d_ws, size_t ws_size,
                              hipStream_t stream)
{
  const float* x   = (const float*)d_in[0];
  const float* Wq  = (const float*)d_in[1];
  const float* bq  = (const float*)d_in[2];
  const float* Wk  = (const float*)d_in[3];
  const float* bk  = (const float*)d_in[4];
  const float* Wv  = (const float*)d_in[5];
  const float* bv  = (const float*)d_in[6];
  const float* W1  = (const float*)d_in[7];
  const float* b1  = (const float*)d_in[8];
  const float* W2  = (const float*)d_in[9];
  const float* b2  = (const float*)d_in[10];
  const float* g1  = (const float*)d_in[11];
  const float* be1 = (const float*)d_in[12];
  const float* g2  = (const float*)d_in[13];
  const float* be2 = (const float*)d_in[14];
  (void)in_sizes; (void)n_in; (void)out_size;

  char* ws = (char*)d_ws;
  __bf16*   qb  = (__bf16*)(ws + OFF_Q);
  __bf16*   kb  = (__bf16*)(ws + OFF_K);
  __bf16*   vT  = (__bf16*)(ws + OFF_VT);
  float*    x2  = (float*)(ws + OFF_X2);
  __bf16*   wbf = (__bf16*)(ws + OFF_W);
  __bf16*   h1  = (__bf16*)(ws + OFF_POOL);
  __bf16*   vb  = (__bf16*)(ws + OFF_POOL + SZ_ACT);
  _Float16* Sp  = (_Float16*)(ws + OFF_POOL);
  __bf16*   h2  = h1;
  __bf16*   h3  = qb;

  const bool big = ws_size >= OFF_POOL + (size_t)NBATCH*SEQLEN*SEQLEN*2;

  k_cvt5<<<dim3(576,5,1),256,0,stream>>>(Wq,Wk,Wv,W1,W2,wbf);
  k_layernorm<<<dim3(4096),256,0,stream>>>(x, g1, be1, h1);
  k_qkv<<<dim3(2304),256,0,stream>>>(h1, wbf, bq, bk, bv, qb, kb, vb);
  k_transpose_v<<<dim3(32,12,8),256,0,stream>>>(vb, vT);

  if (big){
    k_s<<<dim3(2048),256,0,stream>>>(qb, kb, Sp, 256);
    k_softmax<<<dim3(4096),256,0,stream>>>(Sp);
    k_pv<<<dim3(768),256,0,stream>>>((const __bf16*)Sp, vT, x, x2, 0, 96);
  } else {
    for (int c=0;c<2;c++){
      const size_t qoff = (size_t)c*4*SEQLEN*D_MODEL;
      k_s<<<dim3(1024),256,0,stream>>>(qb + qoff, kb + qoff, Sp, 128);
      k_softmax<<<dim3(2048),256,0,stream>>>(Sp);
      k_pv<<<dim3(384),256,0,stream>>>((const __bf16*)Sp, vT, x, x2, c*4, 48);
    }
  }

  k_layernorm<<<dim3(4096),256,0,stream>>>(x2, g2, be2, h2);
  k_mlp<0><<<dim3(768),256,0,stream>>>(h2, wbf + (size_t)3*589824, b1, nullptr, h3);
  k_mlp<1><<<dim3(768),256,0,stream>>>(h3, wbf + (size_t)4*589824, b2, x2, d_out);
}